// Round 4
// baseline (145.321 us; speedup 1.0000x reference)
//
#include <hip/hip_runtime.h>
#include <hip/hip_bf16.h>

#define NH 16
#define DH 64
#define LL 2048
#define DM 1024
#define SCALE2 0.1803368801111204f   /* 0.125 * log2(e) */
#define MASKED2 -1.0e9f              /* log2-domain mask fill */
#define DEFER_THR2 11.5f             /* ~8 nats in log2 units (T13) */

typedef __attribute__((ext_vector_type(4))) float f32x4;
typedef __attribute__((ext_vector_type(8))) short bf16x8;
typedef __attribute__((ext_vector_type(4))) short bf16x4;

__device__ __forceinline__ unsigned pk2(float lo, float hi) {
    __hip_bfloat162 h = __float22bfloat162_rn(make_float2(lo, hi));
    union { __hip_bfloat162 h; unsigned u; } c; c.h = h; return c.u;
}
__device__ __forceinline__ bf16x8 cvt8(float4 a, float4 b) {
    union { bf16x8 v; unsigned u[4]; } r;
    r.u[0] = pk2(a.x, a.y); r.u[1] = pk2(a.z, a.w);
    r.u[2] = pk2(b.x, b.y); r.u[3] = pk2(b.z, b.w);
    return r.v;
}

// ---- mask pre-pack: [B][L][L] (int32 or byte bool) -> bit per key ----
__global__ __launch_bounds__(256) void pack_mask(const void* __restrict__ mask,
                                                 unsigned* __restrict__ bits)
{
    const int tid = threadIdx.x;
    const int lane = tid & 63;
    const int* mw = (const int*)mask;
    unsigned long long bad = __ballot((unsigned)mw[lane] > 1u);
    const bool is_int = (bad == 0ULL);

    const int wid = blockIdx.x * 256 + tid;   // 0 .. 2*LL*64-1
    const int q64 = wid >> 6;
    const int w = wid & 63;
    unsigned m = 0;
    if (is_int) {
        const int* p = (const int*)mask + (size_t)q64 * LL + w * 32;
        #pragma unroll
        for (int j = 0; j < 32; j += 4) {
            int4 v = *(const int4*)(p + j);
            m |= (v.x ? 1u : 0u) << j;
            m |= (v.y ? 1u : 0u) << (j + 1);
            m |= (v.z ? 1u : 0u) << (j + 2);
            m |= (v.w ? 1u : 0u) << (j + 3);
        }
    } else {
        const unsigned* p = (const unsigned*)((const unsigned char*)mask
                                              + (size_t)q64 * LL + w * 32);
        #pragma unroll
        for (int j = 0; j < 8; ++j) {
            unsigned v = p[j];
            m |= (v & 1u) << (4 * j);
            m |= ((v >> 8) & 1u) << (4 * j + 1);
            m |= ((v >> 16) & 1u) << (4 * j + 2);
            m |= ((v >> 24) & 1u) << (4 * j + 3);
        }
    }
    bits[wid] = m;
}

__global__ __launch_bounds__(256) void mha_fwd(
    const float* __restrict__ Q, const float* __restrict__ K,
    const float* __restrict__ V, const unsigned* __restrict__ mbits,
    float* __restrict__ out)
{
    const int qblk = blockIdx.x;
    const int h = blockIdx.y;
    const int b = blockIdx.z;
    const int tid = threadIdx.x;
    const int w = tid >> 6;
    const int lane = tid & 63;
    const int lq = lane & 15;     // q-row within strip (col of S^T)
    const int g = lane >> 4;      // 4-lane-group 0..3

    const int qbase = qblk * 64 + w * 16;
    const float* Qp = Q + ((size_t)b * LL + qbase) * DM + h * DH;
    const float* Kp = K + (size_t)b * LL * DM + h * DH;
    const float* Vp = V + (size_t)b * LL * DM + h * DH;
    const unsigned* Wp = mbits + ((size_t)b * LL + qbase + lq) * 64;

    // K tile [key][dk] bf16, 128B row, XOR-swizzled in 8-short groups (T2):
    // element (row, col) lives at Kt[row][ ((col>>3)^(row&7))*8 + (col&7) ]
    __shared__ short Kt[64][64];
    // V^T tile [dv][key] bf16, stride 72 shorts (dword stride 36 == 4 mod 32
    // -> the 16-lane x 4-group ds_read_b64 pattern is 2-way = free)
    __shared__ short Vt[64][72];

    // Q fragments: qf[half][i] = Q[qbase+lq][32*half + 8g + i]
    bf16x8 qf[2];
    {
        const float* qrow = Qp + (size_t)lq * DM;
        #pragma unroll
        for (int half = 0; half < 2; ++half) {
            const float* src = qrow + half * 32 + g * 8;
            qf[half] = cvt8(*(const float4*)(src), *(const float4*)(src + 4));
        }
    }

    f32x4 o[4];
    #pragma unroll
    for (int t = 0; t < 4; ++t) o[t] = (f32x4){0.f, 0.f, 0.f, 0.f};
    float m_run = -INFINITY;
    float l_run = 0.f;

    const int skey = tid >> 2;          // K staging: key row (per-block row)
    const int sc8 = (tid & 3) * 2;      // K staging: first 8-short col group
    const int p_ = tid & 31;            // V staging: key pair
    const int dvg = tid >> 5;           // V staging: dv group of 8

    const float* ksrc0 = Kp + (size_t)skey * DM + sc8 * 8;
    const float* vsrc0 = Vp + (size_t)(2 * p_) * DM + dvg * 8;

    // T14 prologue: issue tile-0 loads
    float4 kr0, kr1, kr2, kr3, vr0, vr1, vr2, vr3;
    kr0 = *(const float4*)(ksrc0);
    kr1 = *(const float4*)(ksrc0 + 4);
    kr2 = *(const float4*)(ksrc0 + 8);
    kr3 = *(const float4*)(ksrc0 + 12);
    vr0 = *(const float4*)(vsrc0);
    vr1 = *(const float4*)(vsrc0 + 4);
    vr2 = *(const float4*)(vsrc0 + DM);
    vr3 = *(const float4*)(vsrc0 + DM + 4);

    #pragma unroll 1
    for (int kt = 0; kt < LL; kt += 64) {
        __syncthreads();               // prev tile's LDS reads done
        {   // K: convert staged regs, swizzled b128 writes
            *(bf16x8*)&Kt[skey][((sc8 ^ (skey & 7)) << 3)] = cvt8(kr0, kr1);
            *(bf16x8*)&Kt[skey][(((sc8 + 1) ^ (skey & 7)) << 3)] = cvt8(kr2, kr3);
        }
        {   // V^T: pack pairs of key rows
            float av[8] = {vr0.x, vr0.y, vr0.z, vr0.w, vr1.x, vr1.y, vr1.z, vr1.w};
            float bv[8] = {vr2.x, vr2.y, vr2.z, vr2.w, vr3.x, vr3.y, vr3.z, vr3.w};
            #pragma unroll
            for (int j = 0; j < 8; ++j)
                *(unsigned*)&Vt[8 * dvg + j][2 * p_] = pk2(av[j], bv[j]);
        }
        __syncthreads();

        if (kt + 64 < LL) {            // T14: issue next tile's loads now
            const float* ks = ksrc0 + (size_t)(kt + 64) * DM;
            const float* vs = vsrc0 + (size_t)(kt + 64) * DM;
            kr0 = *(const float4*)(ks);
            kr1 = *(const float4*)(ks + 4);
            kr2 = *(const float4*)(ks + 8);
            kr3 = *(const float4*)(ks + 12);
            vr0 = *(const float4*)(vs);
            vr1 = *(const float4*)(vs + 4);
            vr2 = *(const float4*)(vs + DM);
            vr3 = *(const float4*)(vs + DM + 4);
        }

        unsigned mlo = Wp[(kt >> 5)];
        unsigned mhi = Wp[(kt >> 5) + 1];

        // ---- 8 S^T MFMAs ----
        f32x4 s[4];
        #pragma unroll
        for (int ki = 0; ki < 4; ++ki) {
            const int row = ki * 16 + lq;
            bf16x8 k0 = *(const bf16x8*)&Kt[row][((g ^ (lq & 7)) << 3)];
            bf16x8 k1 = *(const bf16x8*)&Kt[row][(((4 + g) ^ (lq & 7)) << 3)];
            f32x4 acc = (f32x4){0.f, 0.f, 0.f, 0.f};
            acc = __builtin_amdgcn_mfma_f32_16x16x32_bf16(k0, qf[0], acc, 0, 0, 0);
            acc = __builtin_amdgcn_mfma_f32_16x16x32_bf16(k1, qf[1], acc, 0, 0, 0);
            s[ki] = acc;
        }

        // ---- mask + scale (log2 domain) ----
        float sv[16];
        #pragma unroll
        for (int ki = 0; ki < 4; ++ki) {
            unsigned nib = ((ki < 2 ? mlo : mhi) >> (16 * (ki & 1) + 4 * g)) & 15u;
            #pragma unroll
            for (int r = 0; r < 4; ++r) {
                float x = s[ki][r] * SCALE2;
                sv[ki * 4 + r] = (nib & (1u << r)) ? MASKED2 : x;
            }
        }
        // max tree
        float m0 = fmaxf(fmaxf(sv[0], sv[1]), fmaxf(sv[2], sv[3]));
        float m1 = fmaxf(fmaxf(sv[4], sv[5]), fmaxf(sv[6], sv[7]));
        float m2 = fmaxf(fmaxf(sv[8], sv[9]), fmaxf(sv[10], sv[11]));
        float m3 = fmaxf(fmaxf(sv[12], sv[13]), fmaxf(sv[14], sv[15]));
        float pmax = fmaxf(fmaxf(m0, m1), fmaxf(m2, m3));
        pmax = fmaxf(pmax, __shfl_xor(pmax, 16, 64));
        pmax = fmaxf(pmax, __shfl_xor(pmax, 32, 64));

        // defer-max (T13): rescale at most when growth exceeds threshold
        if (!__all(pmax - m_run <= DEFER_THR2)) {
            float newm = fmaxf(m_run, pmax);
            float alpha = exp2f(m_run - newm);
            m_run = newm;
            l_run *= alpha;
            #pragma unroll
            for (int t = 0; t < 4; ++t) {
                o[t][0] *= alpha; o[t][1] *= alpha;
                o[t][2] *= alpha; o[t][3] *= alpha;
            }
        }

        float p[16];
        #pragma unroll
        for (int i = 0; i < 16; ++i) p[i] = exp2f(sv[i] - m_run);
        float s0 = (p[0] + p[1]) + (p[2] + p[3]);
        float s1 = (p[4] + p[5]) + (p[6] + p[7]);
        float s2 = (p[8] + p[9]) + (p[10] + p[11]);
        float s3 = (p[12] + p[13]) + (p[14] + p[15]);
        l_run += (s0 + s1) + (s2 + s3);

        #pragma unroll
        for (int ki = 0; ki < 4; ++ki) {
            union { bf16x4 v; unsigned u[2]; } pf;
            pf.u[0] = pk2(p[ki * 4 + 0], p[ki * 4 + 1]);
            pf.u[1] = pk2(p[ki * 4 + 2], p[ki * 4 + 3]);
            #pragma unroll
            for (int t = 0; t < 4; ++t) {
                bf16x4 vf = *(const bf16x4*)&Vt[16 * t + lq][ki * 16 + 4 * g];
                o[t] = __builtin_amdgcn_mfma_f32_16x16x16bf16_1k(vf, pf.v, o[t], 0, 0, 0);
            }
        }
    }

    // finish: sum l across the 4 lane-groups, normalize, store O^T
    l_run += __shfl_xor(l_run, 16, 64);
    l_run += __shfl_xor(l_run, 32, 64);
    float inv = __builtin_amdgcn_rcpf(l_run);
    float* orow = out + ((size_t)b * LL + qbase + lq) * DM + h * DH;
    #pragma unroll
    for (int t = 0; t < 4; ++t) {
        float4 ov;
        ov.x = o[t][0] * inv; ov.y = o[t][1] * inv;
        ov.z = o[t][2] * inv; ov.w = o[t][3] * inv;
        *(float4*)(orow + 16 * t + 4 * g) = ov;
    }
}

extern "C" void kernel_launch(void* const* d_in, const int* in_sizes, int n_in,
                              void* d_out, int out_size, void* d_ws, size_t ws_size,
                              hipStream_t stream) {
    const float* Q = (const float*)d_in[0];
    const float* K = (const float*)d_in[1];
    const float* V = (const float*)d_in[2];
    const void* mask = d_in[3];
    float* out = (float*)d_out;
    unsigned* bits = (unsigned*)d_ws;   // 2*LL*64 u32 = 1 MB

    pack_mask<<<dim3(2 * LL * 64 / 256), dim3(256), 0, stream>>>(mask, bits);
    dim3 grid(LL / 64, NH, 2);
    mha_fwd<<<grid, dim3(256), 0, stream>>>(Q, K, V, bits, out);
}

// Round 5
// 136.527 us; speedup vs baseline: 1.0644x; 1.0644x over previous
//
#include <hip/hip_runtime.h>
#include <hip/hip_bf16.h>

#define NH 16
#define DH 64
#define LL 2048
#define DM 1024
#define SCALE2 0.1803368801111204f   /* 0.125 * log2(e) */
#define M_STATIC 10.0f               /* static log2-domain softmax shift */
#define THR_C 6.0f                   /* guard: fires only if score > ~11 sigma */
#define NT (LL / 64)

typedef __attribute__((ext_vector_type(4))) float f32x4;
typedef __attribute__((ext_vector_type(8))) short bf16x8;
typedef __attribute__((ext_vector_type(4))) short bf16x4;

__device__ __forceinline__ unsigned pk2(float lo, float hi) {
    __hip_bfloat162 h = __float22bfloat162_rn(make_float2(lo, hi));
    union { __hip_bfloat162 h; unsigned u; } c; c.h = h; return c.u;
}
__device__ __forceinline__ bf16x8 cvt8(float4 a, float4 b) {
    union { bf16x8 v; unsigned u[4]; } r;
    r.u[0] = pk2(a.x, a.y); r.u[1] = pk2(a.z, a.w);
    r.u[2] = pk2(b.x, b.y); r.u[3] = pk2(b.z, b.w);
    return r.v;
}

// ---- mask pre-pack: [B][L][L] (int32 or byte bool) -> bit per key ----
__global__ __launch_bounds__(256) void pack_mask(const void* __restrict__ mask,
                                                 unsigned* __restrict__ bits)
{
    const int tid = threadIdx.x;
    const int lane = tid & 63;
    const int* mw = (const int*)mask;
    unsigned long long bad = __ballot((unsigned)mw[lane] > 1u);
    const bool is_int = (bad == 0ULL);

    const int wid = blockIdx.x * 256 + tid;   // 0 .. 2*LL*64-1
    const int q64 = wid >> 6;
    const int w = wid & 63;
    unsigned m = 0;
    if (is_int) {
        const int* p = (const int*)mask + (size_t)q64 * LL + w * 32;
        #pragma unroll
        for (int j = 0; j < 32; j += 4) {
            int4 v = *(const int4*)(p + j);
            m |= (v.x ? 1u : 0u) << j;
            m |= (v.y ? 1u : 0u) << (j + 1);
            m |= (v.z ? 1u : 0u) << (j + 2);
            m |= (v.w ? 1u : 0u) << (j + 3);
        }
    } else {
        const unsigned* p = (const unsigned*)((const unsigned char*)mask
                                              + (size_t)q64 * LL + w * 32);
        #pragma unroll
        for (int j = 0; j < 8; ++j) {
            unsigned v = p[j];
            m |= (v & 1u) << (4 * j);
            m |= ((v >> 8) & 1u) << (4 * j + 1);
            m |= ((v >> 16) & 1u) << (4 * j + 2);
            m |= ((v >> 24) & 1u) << (4 * j + 3);
        }
    }
    bits[wid] = m;
}

__global__ __launch_bounds__(256, 4) void mha_fwd(
    const float* __restrict__ Q, const float* __restrict__ K,
    const float* __restrict__ V, const unsigned* __restrict__ mbits,
    float* __restrict__ out)
{
    const int qblk = blockIdx.x;
    const int h = blockIdx.y;
    const int b = blockIdx.z;
    const int tid = threadIdx.x;
    const int w = tid >> 6;
    const int lane = tid & 63;
    const int lq = lane & 15;     // q-row within strip (col of S^T)
    const int g = lane >> 4;      // 4-lane-group 0..3

    const int qbase = qblk * 64 + w * 16;
    const float* Qp = Q + ((size_t)b * LL + qbase) * DM + h * DH;
    const float* Kp = K + (size_t)b * LL * DM + h * DH;
    const float* Vp = V + (size_t)b * LL * DM + h * DH;
    const unsigned* Wp = mbits + ((size_t)b * LL + qbase + lq) * 64;

    // round-3-proven layouts, double-buffered:
    // K tile [key][dk] bf16, stride 72 shorts (144 B)
    __shared__ short Kt[2][64][72];
    // V^T tile [dv][key] bf16, stride 68 shorts (136 B)
    __shared__ short Vt[2][64][68];

    // Q fragments: qf[half][i] = Q[qbase+lq][32*half + 8g + i]
    bf16x8 qf[2];
    {
        const float* qrow = Qp + (size_t)lq * DM;
        #pragma unroll
        for (int half = 0; half < 2; ++half) {
            const float* src = qrow + half * 32 + g * 8;
            qf[half] = cvt8(*(const float4*)(src), *(const float4*)(src + 4));
        }
    }

    f32x4 o[4];
    #pragma unroll
    for (int t = 0; t < 4; ++t) o[t] = (f32x4){0.f, 0.f, 0.f, 0.f};
    float m_run = M_STATIC;
    float l_run = 0.f;

    const int skey = tid >> 2;          // K staging: key row
    const int sdq = (tid & 3) * 16;     // K staging: dk quarter
    const int p_ = tid & 31;            // V staging: key pair
    const int dvg = tid >> 5;           // V staging: dv group of 8

    const float* ksrc0 = Kp + (size_t)skey * DM + sdq;
    const float* vsrc0 = Vp + (size_t)(2 * p_) * DM + dvg * 8;

    float4 kr0, kr1, kr2, kr3, vr0, vr1, vr2, vr3;
    // prologue: load + stage tile 0 into buffer 0
    kr0 = *(const float4*)(ksrc0);
    kr1 = *(const float4*)(ksrc0 + 4);
    kr2 = *(const float4*)(ksrc0 + 8);
    kr3 = *(const float4*)(ksrc0 + 12);
    vr0 = *(const float4*)(vsrc0);
    vr1 = *(const float4*)(vsrc0 + 4);
    vr2 = *(const float4*)(vsrc0 + DM);
    vr3 = *(const float4*)(vsrc0 + DM + 4);
    {
        *(bf16x8*)&Kt[0][skey][sdq] = cvt8(kr0, kr1);
        *(bf16x8*)&Kt[0][skey][sdq + 8] = cvt8(kr2, kr3);
        float av[8] = {vr0.x, vr0.y, vr0.z, vr0.w, vr1.x, vr1.y, vr1.z, vr1.w};
        float bv[8] = {vr2.x, vr2.y, vr2.z, vr2.w, vr3.x, vr3.y, vr3.z, vr3.w};
        #pragma unroll
        for (int j = 0; j < 8; ++j)
            *(unsigned*)&Vt[0][8 * dvg + j][2 * p_] = pk2(av[j], bv[j]);
    }
    __syncthreads();

    #pragma unroll 1
    for (int t = 0; t < NT; ++t) {
        const int cur = t & 1;
        const bool has_next = (t + 1 < NT);
        if (has_next) {   // T14: issue next tile's loads NOW...
            const float* ks = ksrc0 + (size_t)(t + 1) * 64 * DM;
            const float* vs = vsrc0 + (size_t)(t + 1) * 64 * DM;
            kr0 = *(const float4*)(ks);
            kr1 = *(const float4*)(ks + 4);
            kr2 = *(const float4*)(ks + 8);
            kr3 = *(const float4*)(ks + 12);
            vr0 = *(const float4*)(vs);
            vr1 = *(const float4*)(vs + 4);
            vr2 = *(const float4*)(vs + DM);
            vr3 = *(const float4*)(vs + DM + 4);
        }
        __builtin_amdgcn_sched_barrier(0);  // ...and pin them (no sinking)

        unsigned long long m64 = *(const unsigned long long*)(Wp + 2 * t);

        // ---- 8 S^T MFMAs ----
        f32x4 s[4];
        __builtin_amdgcn_s_setprio(1);
        #pragma unroll
        for (int ki = 0; ki < 4; ++ki) {
            const int row = ki * 16 + lq;
            bf16x8 k0 = *(const bf16x8*)&Kt[cur][row][8 * g];
            bf16x8 k1 = *(const bf16x8*)&Kt[cur][row][32 + 8 * g];
            f32x4 acc = (f32x4){0.f, 0.f, 0.f, 0.f};
            acc = __builtin_amdgcn_mfma_f32_16x16x32_bf16(k0, qf[0], acc, 0, 0, 0);
            acc = __builtin_amdgcn_mfma_f32_16x16x32_bf16(k1, qf[1], acc, 0, 0, 0);
            s[ki] = acc;
        }
        __builtin_amdgcn_s_setprio(0);

        // ---- static-max softmax (log2 domain, no cross-lane in common path)
        float sv[16];
        #pragma unroll
        for (int ki = 0; ki < 4; ++ki)
            #pragma unroll
            for (int r = 0; r < 4; ++r)
                sv[ki * 4 + r] = fmaf(s[ki][r], SCALE2, -m_run);

        float x0 = fmaxf(fmaxf(sv[0], sv[1]), fmaxf(sv[2], sv[3]));
        float x1 = fmaxf(fmaxf(sv[4], sv[5]), fmaxf(sv[6], sv[7]));
        float x2 = fmaxf(fmaxf(sv[8], sv[9]), fmaxf(sv[10], sv[11]));
        float x3 = fmaxf(fmaxf(sv[12], sv[13]), fmaxf(sv[14], sv[15]));
        float pmax = fmaxf(fmaxf(x0, x1), fmaxf(x2, x3));
        if (!__all(pmax <= THR_C)) {   // rare guard: full shuffled rescale
            float tmax = fmaxf(pmax, __shfl_xor(pmax, 16, 64));
            tmax = fmaxf(tmax, __shfl_xor(tmax, 32, 64));
            float shift = fmaxf(tmax, 0.f);
            float alpha = exp2f(-shift);
            m_run += shift;
            l_run *= alpha;
            #pragma unroll
            for (int q = 0; q < 4; ++q) {
                o[q][0] *= alpha; o[q][1] *= alpha;
                o[q][2] *= alpha; o[q][3] *= alpha;
            }
            #pragma unroll
            for (int i = 0; i < 16; ++i) sv[i] -= shift;
        }

        float p[16];
        #pragma unroll
        for (int i = 0; i < 16; ++i) p[i] = exp2f(sv[i]);
        // mask -> exact zero (matches reference: exp of -1.25e9 underflows)
        #pragma unroll
        for (int ki = 0; ki < 4; ++ki) {
            unsigned nib = (unsigned)(m64 >> (ki * 16 + 4 * g)) & 15u;
            #pragma unroll
            for (int r = 0; r < 4; ++r)
                p[ki * 4 + r] = (nib & (1u << r)) ? 0.f : p[ki * 4 + r];
        }
        float s0 = (p[0] + p[1]) + (p[2] + p[3]);
        float s1 = (p[4] + p[5]) + (p[6] + p[7]);
        float s2 = (p[8] + p[9]) + (p[10] + p[11]);
        float s3 = (p[12] + p[13]) + (p[14] + p[15]);
        l_run += (s0 + s1) + (s2 + s3);

        // ---- PV ----
        __builtin_amdgcn_s_setprio(1);
        #pragma unroll
        for (int ki = 0; ki < 4; ++ki) {
            union { bf16x4 v; unsigned u[2]; } pf;
            pf.u[0] = pk2(p[ki * 4 + 0], p[ki * 4 + 1]);
            pf.u[1] = pk2(p[ki * 4 + 2], p[ki * 4 + 3]);
            #pragma unroll
            for (int q = 0; q < 4; ++q) {
                bf16x4 vf = *(const bf16x4*)&Vt[cur][16 * q + lq][ki * 16 + 4 * g];
                o[q] = __builtin_amdgcn_mfma_f32_16x16x16bf16_1k(vf, pf.v, o[q], 0, 0, 0);
            }
        }
        __builtin_amdgcn_s_setprio(0);

        if (has_next) {   // stage next tile into the other buffer
            const int nxt = cur ^ 1;
            *(bf16x8*)&Kt[nxt][skey][sdq] = cvt8(kr0, kr1);
            *(bf16x8*)&Kt[nxt][skey][sdq + 8] = cvt8(kr2, kr3);
            float av[8] = {vr0.x, vr0.y, vr0.z, vr0.w, vr1.x, vr1.y, vr1.z, vr1.w};
            float bv[8] = {vr2.x, vr2.y, vr2.z, vr2.w, vr3.x, vr3.y, vr3.z, vr3.w};
            #pragma unroll
            for (int j = 0; j < 8; ++j)
                *(unsigned*)&Vt[nxt][8 * dvg + j][2 * p_] = pk2(av[j], bv[j]);
        }
        __syncthreads();   // single barrier per tile
    }

    // finish: sum l across the 4 lane-groups, normalize, store O^T
    l_run += __shfl_xor(l_run, 16, 64);
    l_run += __shfl_xor(l_run, 32, 64);
    float inv = __builtin_amdgcn_rcpf(l_run);
    float* orow = out + ((size_t)b * LL + qbase + lq) * DM + h * DH;
    #pragma unroll
    for (int t = 0; t < 4; ++t) {
        float4 ov;
        ov.x = o[t][0] * inv; ov.y = o[t][1] * inv;
        ov.z = o[t][2] * inv; ov.w = o[t][3] * inv;
        *(float4*)(orow + 16 * t + 4 * g) = ov;
    }
}

extern "C" void kernel_launch(void* const* d_in, const int* in_sizes, int n_in,
                              void* d_out, int out_size, void* d_ws, size_t ws_size,
                              hipStream_t stream) {
    const float* Q = (const float*)d_in[0];
    const float* K = (const float*)d_in[1];
    const float* V = (const float*)d_in[2];
    const void* mask = d_in[3];
    float* out = (float*)d_out;
    unsigned* bits = (unsigned*)d_ws;   // 2*LL*64 u32 = 1 MB

    pack_mask<<<dim3(2 * LL * 64 / 256), dim3(256), 0, stream>>>(mask, bits);
    dim3 grid(LL / 64, NH, 2);
    mha_fwd<<<grid, dim3(256), 0, stream>>>(Q, K, V, bits, out);
}

// Round 6
// 108.841 us; speedup vs baseline: 1.3352x; 1.2544x over previous
//
#include <hip/hip_runtime.h>
#include <hip/hip_bf16.h>

#define NH 16
#define DH 64
#define LL 2048
#define DM 1024
#define SCALE2 0.1803368801111204f   /* 0.125 * log2(e) */
#define M_STATIC 10.0f               /* static log2-domain softmax shift */
#define THR_C 6.0f                   /* guard fires only if score > ~11 sigma */
#define NT (LL / 64)

typedef __attribute__((ext_vector_type(4))) float f32x4;
typedef __attribute__((ext_vector_type(8))) short bf16x8;
typedef __attribute__((ext_vector_type(4))) short bf16x4;

__device__ __forceinline__ unsigned pk2(float lo, float hi) {
    __hip_bfloat162 h = __float22bfloat162_rn(make_float2(lo, hi));
    union { __hip_bfloat162 h; unsigned u; } c; c.h = h; return c.u;
}
__device__ __forceinline__ bf16x8 cvt8(float4 a, float4 b) {
    union { bf16x8 v; unsigned u[4]; } r;
    r.u[0] = pk2(a.x, a.y); r.u[1] = pk2(a.z, a.w);
    r.u[2] = pk2(b.x, b.y); r.u[3] = pk2(b.z, b.w);
    return r.v;
}

// ---- mask pre-pack: [B][L][L] (int32 or byte bool) -> bit per key ----
__global__ __launch_bounds__(256) void pack_mask(const void* __restrict__ mask,
                                                 unsigned* __restrict__ bits)
{
    const int tid = threadIdx.x;
    const int lane = tid & 63;
    const int* mw = (const int*)mask;
    unsigned long long bad = __ballot((unsigned)mw[lane] > 1u);
    const bool is_int = (bad == 0ULL);

    const int wid = blockIdx.x * 256 + tid;   // 0 .. 2*LL*64-1
    const int q64 = wid >> 6;
    const int w = wid & 63;
    unsigned m = 0;
    if (is_int) {
        const int* p = (const int*)mask + (size_t)q64 * LL + w * 32;
        #pragma unroll
        for (int j = 0; j < 32; j += 4) {
            int4 v = *(const int4*)(p + j);
            m |= (v.x ? 1u : 0u) << j;
            m |= (v.y ? 1u : 0u) << (j + 1);
            m |= (v.z ? 1u : 0u) << (j + 2);
            m |= (v.w ? 1u : 0u) << (j + 3);
        }
    } else {
        const unsigned* p = (const unsigned*)((const unsigned char*)mask
                                              + (size_t)q64 * LL + w * 32);
        #pragma unroll
        for (int j = 0; j < 8; ++j) {
            unsigned v = p[j];
            m |= (v & 1u) << (4 * j);
            m |= ((v >> 8) & 1u) << (4 * j + 1);
            m |= ((v >> 16) & 1u) << (4 * j + 2);
            m |= ((v >> 24) & 1u) << (4 * j + 3);
        }
    }
    bits[wid] = m;
}

// ---- K pre-convert: f32 -> bf16, 8KB per (b,h,ktile), swizzled LDS image ----
// logical (key 0..63, col 0..63) -> tile[key*64 + ((col>>3)^(key&7))*8 + (col&7)]
__global__ __launch_bounds__(256) void prep_k(const float* __restrict__ K,
                                              short* __restrict__ Kb)
{
    const int kt = blockIdx.x, h = blockIdx.y, b = blockIdx.z;
    const int tid = threadIdx.x;
    const int key = tid >> 2;
    const int c8 = (tid & 3) * 2;          // col8-groups {0,2,4,6}, +1
    const float* src = K + ((size_t)b * LL + kt * 64 + key) * DM + h * DH + c8 * 8;
    float4 a = *(const float4*)(src);
    float4 bb = *(const float4*)(src + 4);
    float4 c = *(const float4*)(src + 8);
    float4 d = *(const float4*)(src + 12);
    short* dst = Kb + (((size_t)(b * NH + h) * 32 + kt) << 12);
    *(bf16x8*)&dst[key * 64 + ((c8 ^ (key & 7)) << 3)] = cvt8(a, bb);
    *(bf16x8*)&dst[key * 64 + (((c8 + 1) ^ (key & 7)) << 3)] = cvt8(c, d);
}

// ---- V pre-convert: f32 -> bf16 transposed V^T, swizzled LDS image ----
// logical (dv 0..63, key 0..63) -> tile[dv*64 + ((key>>2)^(dv&15))*4 + (key&3)]
__global__ __launch_bounds__(256) void prep_v(const float* __restrict__ V,
                                              short* __restrict__ Vb)
{
    const int kt = blockIdx.x, h = blockIdx.y, b = blockIdx.z;
    const int tid = threadIdx.x;
    const int kp = tid & 31;              // key pair: keys 2kp, 2kp+1
    const int dv8 = tid >> 5;             // dv group of 8
    const float* s0 = V + ((size_t)b * LL + kt * 64 + 2 * kp) * DM + h * DH + dv8 * 8;
    float4 a0 = *(const float4*)(s0);
    float4 a1 = *(const float4*)(s0 + 4);
    float4 b0 = *(const float4*)(s0 + DM);
    float4 b1 = *(const float4*)(s0 + DM + 4);
    float av[8] = {a0.x, a0.y, a0.z, a0.w, a1.x, a1.y, a1.z, a1.w};
    float bv[8] = {b0.x, b0.y, b0.z, b0.w, b1.x, b1.y, b1.z, b1.w};
    short* dst = Vb + (((size_t)(b * NH + h) * 32 + kt) << 12);
    #pragma unroll
    for (int j = 0; j < 8; ++j) {
        int dv = dv8 * 8 + j;
        int off = dv * 64 + (((kp >> 1) ^ (dv & 15)) << 2) + 2 * (kp & 1);
        *(unsigned*)&dst[off] = pk2(av[j], bv[j]);
    }
}

// ---- main: 512 threads (8 waves x 16 q-rows), gload_lds + counted vmcnt ----
__global__ __launch_bounds__(512, 4) void mha_fwd2(
    const float* __restrict__ Q, const short* __restrict__ Kb,
    const short* __restrict__ Vb, const unsigned* __restrict__ mbits,
    float* __restrict__ out)
{
    // XCD-aware 1D swizzle: xcd = bid%8 owns (b,h) pairs {4*xcd..4*xcd+3}
    const int bid = blockIdx.x;
    const int xcd = bid & 7;
    const int j = bid >> 3;               // 0..63
    const int pair = xcd * 4 + (j >> 4);  // 0..31
    const int qblk = j & 15;
    const int h = pair & 15;
    const int b = pair >> 4;

    const int tid = threadIdx.x;
    const int w = tid >> 6;               // wave 0..7
    const int lane = tid & 63;
    const int lq = lane & 15;
    const int g = lane >> 4;

    const int qbase = qblk * 128 + w * 16;

    __shared__ short Kt[2][4096];
    __shared__ short Vt[2][4096];

    const short* Ktile0 = Kb + ((size_t)(b * NH + h) << 17);
    const short* Vtile0 = Vb + ((size_t)(b * NH + h) << 17);
    const unsigned* Wp = mbits + ((size_t)b * LL + qbase + lq) * 64;

    // prologue: issue tile-0 LDS loads + tile-0 mask
    __builtin_amdgcn_global_load_lds((const unsigned*)(Ktile0 + w * 512 + lane * 8),
                                     (unsigned*)&Kt[0][w * 512], 16, 0, 0);
    __builtin_amdgcn_global_load_lds((const unsigned*)(Vtile0 + w * 512 + lane * 8),
                                     (unsigned*)&Vt[0][w * 512], 16, 0, 0);
    unsigned long long mnext = *(const unsigned long long*)(Wp);

    // Q fragments: qf[half][i] = Q[qbase+lq][32*half + 8g + i]
    bf16x8 qf[2];
    {
        const float* qrow = Q + ((size_t)b * LL + qbase + lq) * DM + h * DH;
        #pragma unroll
        for (int half = 0; half < 2; ++half) {
            const float* src = qrow + half * 32 + g * 8;
            qf[half] = cvt8(*(const float4*)(src), *(const float4*)(src + 4));
        }
    }

    f32x4 o[4];
    #pragma unroll
    for (int t = 0; t < 4; ++t) o[t] = (f32x4){0.f, 0.f, 0.f, 0.f};
    float m_run = M_STATIC;
    float l_run = 0.f;

    asm volatile("s_waitcnt vmcnt(0)" ::: "memory");
    __builtin_amdgcn_s_barrier();

    #pragma unroll 1
    for (int t = 0; t < NT; ++t) {
        const int cur = t & 1;
        const unsigned long long m64 = mnext;
        if (t + 1 < NT) {   // issue next tile's loads; keep them in flight
            const int nxt = cur ^ 1;
            __builtin_amdgcn_global_load_lds(
                (const unsigned*)(Ktile0 + (t + 1) * 4096 + w * 512 + lane * 8),
                (unsigned*)&Kt[nxt][w * 512], 16, 0, 0);
            __builtin_amdgcn_global_load_lds(
                (const unsigned*)(Vtile0 + (t + 1) * 4096 + w * 512 + lane * 8),
                (unsigned*)&Vt[nxt][w * 512], 16, 0, 0);
            mnext = *(const unsigned long long*)(Wp + 2 * (t + 1));
            asm volatile("s_waitcnt vmcnt(3)" ::: "memory");   // drain tile t only
        } else {
            asm volatile("s_waitcnt vmcnt(0)" ::: "memory");
        }
        __builtin_amdgcn_s_barrier();
        __builtin_amdgcn_sched_barrier(0);

        // ---- 8 S^T MFMAs (swizzled b128 reads, 2-way = free) ----
        f32x4 s[4];
        __builtin_amdgcn_s_setprio(1);
        #pragma unroll
        for (int ki = 0; ki < 4; ++ki) {
            const int row = ki * 16 + lq;
            bf16x8 k0 = *(const bf16x8*)&Kt[cur][row * 64 + ((g ^ (lq & 7)) << 3)];
            bf16x8 k1 = *(const bf16x8*)&Kt[cur][row * 64 + (((4 + g) ^ (lq & 7)) << 3)];
            f32x4 acc = (f32x4){0.f, 0.f, 0.f, 0.f};
            acc = __builtin_amdgcn_mfma_f32_16x16x32_bf16(k0, qf[0], acc, 0, 0, 0);
            acc = __builtin_amdgcn_mfma_f32_16x16x32_bf16(k1, qf[1], acc, 0, 0, 0);
            s[ki] = acc;
        }
        __builtin_amdgcn_s_setprio(0);

        // ---- static-max softmax (log2 domain) ----
        float sv[16];
        #pragma unroll
        for (int ki = 0; ki < 4; ++ki)
            #pragma unroll
            for (int r = 0; r < 4; ++r)
                sv[ki * 4 + r] = fmaf(s[ki][r], SCALE2, -m_run);

        float x0 = fmaxf(fmaxf(sv[0], sv[1]), fmaxf(sv[2], sv[3]));
        float x1 = fmaxf(fmaxf(sv[4], sv[5]), fmaxf(sv[6], sv[7]));
        float x2 = fmaxf(fmaxf(sv[8], sv[9]), fmaxf(sv[10], sv[11]));
        float x3 = fmaxf(fmaxf(sv[12], sv[13]), fmaxf(sv[14], sv[15]));
        float pmax = fmaxf(fmaxf(x0, x1), fmaxf(x2, x3));
        if (!__all(pmax <= THR_C)) {   // rare guard: full shuffled rescale
            float tmax = fmaxf(pmax, __shfl_xor(pmax, 16, 64));
            tmax = fmaxf(tmax, __shfl_xor(tmax, 32, 64));
            float shift = fmaxf(tmax, 0.f);
            float alpha = exp2f(-shift);
            m_run += shift;
            l_run *= alpha;
            #pragma unroll
            for (int q = 0; q < 4; ++q) {
                o[q][0] *= alpha; o[q][1] *= alpha;
                o[q][2] *= alpha; o[q][3] *= alpha;
            }
            #pragma unroll
            for (int i = 0; i < 16; ++i) sv[i] -= shift;
        }

        float p[16];
        #pragma unroll
        for (int i = 0; i < 16; ++i) p[i] = exp2f(sv[i]);
        #pragma unroll
        for (int ki = 0; ki < 4; ++ki) {
            unsigned nib = (unsigned)(m64 >> (ki * 16 + 4 * g)) & 15u;
            #pragma unroll
            for (int r = 0; r < 4; ++r)
                p[ki * 4 + r] = (nib & (1u << r)) ? 0.f : p[ki * 4 + r];
        }
        float s0 = (p[0] + p[1]) + (p[2] + p[3]);
        float s1 = (p[4] + p[5]) + (p[6] + p[7]);
        float s2 = (p[8] + p[9]) + (p[10] + p[11]);
        float s3 = (p[12] + p[13]) + (p[14] + p[15]);
        l_run += (s0 + s1) + (s2 + s3);

        // ---- PV (conflict-free swizzled b64 reads) ----
        __builtin_amdgcn_s_setprio(1);
        #pragma unroll
        for (int ki = 0; ki < 4; ++ki) {
            union { bf16x4 v; unsigned u[2]; } pf;
            pf.u[0] = pk2(p[ki * 4 + 0], p[ki * 4 + 1]);
            pf.u[1] = pk2(p[ki * 4 + 2], p[ki * 4 + 3]);
            #pragma unroll
            for (int q = 0; q < 4; ++q) {
                bf16x4 vf = *(const bf16x4*)
                    &Vt[cur][(16 * q + lq) * 64 + (((4 * ki + g) ^ lq) << 2)];
                o[q] = __builtin_amdgcn_mfma_f32_16x16x16bf16_1k(vf, pf.v, o[q], 0, 0, 0);
            }
        }
        __builtin_amdgcn_s_setprio(0);

        __builtin_amdgcn_sched_barrier(0);
        __builtin_amdgcn_s_barrier();   // reads done before next overwrite
    }

    l_run += __shfl_xor(l_run, 16, 64);
    l_run += __shfl_xor(l_run, 32, 64);
    float inv = __builtin_amdgcn_rcpf(l_run);
    float* orow = out + ((size_t)b * LL + qbase + lq) * DM + h * DH;
    #pragma unroll
    for (int t = 0; t < 4; ++t) {
        float4 ov;
        ov.x = o[t][0] * inv; ov.y = o[t][1] * inv;
        ov.z = o[t][2] * inv; ov.w = o[t][3] * inv;
        *(float4*)(orow + 16 * t + 4 * g) = ov;
    }
}

// ================= fallback (round-5 kernel, ws too small) =================
__global__ __launch_bounds__(256, 4) void mha_fwd(
    const float* __restrict__ Q, const float* __restrict__ K,
    const float* __restrict__ V, const unsigned* __restrict__ mbits,
    float* __restrict__ out)
{
    const int qblk = blockIdx.x;
    const int h = blockIdx.y;
    const int b = blockIdx.z;
    const int tid = threadIdx.x;
    const int w = tid >> 6;
    const int lane = tid & 63;
    const int lq = lane & 15;
    const int g = lane >> 4;

    const int qbase = qblk * 64 + w * 16;
    const float* Qp = Q + ((size_t)b * LL + qbase) * DM + h * DH;
    const float* Kp = K + (size_t)b * LL * DM + h * DH;
    const float* Vp = V + (size_t)b * LL * DM + h * DH;
    const unsigned* Wp = mbits + ((size_t)b * LL + qbase + lq) * 64;

    __shared__ short Kt[2][64][72];
    __shared__ short Vt[2][64][68];

    bf16x8 qf[2];
    {
        const float* qrow = Qp + (size_t)lq * DM;
        #pragma unroll
        for (int half = 0; half < 2; ++half) {
            const float* src = qrow + half * 32 + g * 8;
            qf[half] = cvt8(*(const float4*)(src), *(const float4*)(src + 4));
        }
    }

    f32x4 o[4];
    #pragma unroll
    for (int t = 0; t < 4; ++t) o[t] = (f32x4){0.f, 0.f, 0.f, 0.f};
    float m_run = M_STATIC;
    float l_run = 0.f;

    const int skey = tid >> 2;
    const int sdq = (tid & 3) * 16;
    const int p_ = tid & 31;
    const int dvg = tid >> 5;

    const float* ksrc0 = Kp + (size_t)skey * DM + sdq;
    const float* vsrc0 = Vp + (size_t)(2 * p_) * DM + dvg * 8;

    float4 kr0 = *(const float4*)(ksrc0);
    float4 kr1 = *(const float4*)(ksrc0 + 4);
    float4 kr2 = *(const float4*)(ksrc0 + 8);
    float4 kr3 = *(const float4*)(ksrc0 + 12);
    float4 vr0 = *(const float4*)(vsrc0);
    float4 vr1 = *(const float4*)(vsrc0 + 4);
    float4 vr2 = *(const float4*)(vsrc0 + DM);
    float4 vr3 = *(const float4*)(vsrc0 + DM + 4);
    {
        *(bf16x8*)&Kt[0][skey][sdq] = cvt8(kr0, kr1);
        *(bf16x8*)&Kt[0][skey][sdq + 8] = cvt8(kr2, kr3);
        float av[8] = {vr0.x, vr0.y, vr0.z, vr0.w, vr1.x, vr1.y, vr1.z, vr1.w};
        float bv[8] = {vr2.x, vr2.y, vr2.z, vr2.w, vr3.x, vr3.y, vr3.z, vr3.w};
        #pragma unroll
        for (int jj = 0; jj < 8; ++jj)
            *(unsigned*)&Vt[0][8 * dvg + jj][2 * p_] = pk2(av[jj], bv[jj]);
    }
    __syncthreads();

    #pragma unroll 1
    for (int t = 0; t < NT; ++t) {
        const int cur = t & 1;
        const bool has_next = (t + 1 < NT);
        if (has_next) {
            const float* ks = ksrc0 + (size_t)(t + 1) * 64 * DM;
            const float* vs = vsrc0 + (size_t)(t + 1) * 64 * DM;
            kr0 = *(const float4*)(ks);
            kr1 = *(const float4*)(ks + 4);
            kr2 = *(const float4*)(ks + 8);
            kr3 = *(const float4*)(ks + 12);
            vr0 = *(const float4*)(vs);
            vr1 = *(const float4*)(vs + 4);
            vr2 = *(const float4*)(vs + DM);
            vr3 = *(const float4*)(vs + DM + 4);
        }
        __builtin_amdgcn_sched_barrier(0);

        unsigned long long m64 = *(const unsigned long long*)(Wp + 2 * t);

        f32x4 s[4];
        __builtin_amdgcn_s_setprio(1);
        #pragma unroll
        for (int ki = 0; ki < 4; ++ki) {
            const int row = ki * 16 + lq;
            bf16x8 k0 = *(const bf16x8*)&Kt[cur][row][8 * g];
            bf16x8 k1 = *(const bf16x8*)&Kt[cur][row][32 + 8 * g];
            f32x4 acc = (f32x4){0.f, 0.f, 0.f, 0.f};
            acc = __builtin_amdgcn_mfma_f32_16x16x32_bf16(k0, qf[0], acc, 0, 0, 0);
            acc = __builtin_amdgcn_mfma_f32_16x16x32_bf16(k1, qf[1], acc, 0, 0, 0);
            s[ki] = acc;
        }
        __builtin_amdgcn_s_setprio(0);

        float sv[16];
        #pragma unroll
        for (int ki = 0; ki < 4; ++ki)
            #pragma unroll
            for (int r = 0; r < 4; ++r)
                sv[ki * 4 + r] = fmaf(s[ki][r], SCALE2, -m_run);

        float x0 = fmaxf(fmaxf(sv[0], sv[1]), fmaxf(sv[2], sv[3]));
        float x1 = fmaxf(fmaxf(sv[4], sv[5]), fmaxf(sv[6], sv[7]));
        float x2 = fmaxf(fmaxf(sv[8], sv[9]), fmaxf(sv[10], sv[11]));
        float x3 = fmaxf(fmaxf(sv[12], sv[13]), fmaxf(sv[14], sv[15]));
        float pmax = fmaxf(fmaxf(x0, x1), fmaxf(x2, x3));
        if (!__all(pmax <= THR_C)) {
            float tmax = fmaxf(pmax, __shfl_xor(pmax, 16, 64));
            tmax = fmaxf(tmax, __shfl_xor(tmax, 32, 64));
            float shift = fmaxf(tmax, 0.f);
            float alpha = exp2f(-shift);
            m_run += shift;
            l_run *= alpha;
            #pragma unroll
            for (int q = 0; q < 4; ++q) {
                o[q][0] *= alpha; o[q][1] *= alpha;
                o[q][2] *= alpha; o[q][3] *= alpha;
            }
            #pragma unroll
            for (int i = 0; i < 16; ++i) sv[i] -= shift;
        }

        float p[16];
        #pragma unroll
        for (int i = 0; i < 16; ++i) p[i] = exp2f(sv[i]);
        #pragma unroll
        for (int ki = 0; ki < 4; ++ki) {
            unsigned nib = (unsigned)(m64 >> (ki * 16 + 4 * g)) & 15u;
            #pragma unroll
            for (int r = 0; r < 4; ++r)
                p[ki * 4 + r] = (nib & (1u << r)) ? 0.f : p[ki * 4 + r];
        }
        float s0 = (p[0] + p[1]) + (p[2] + p[3]);
        float s1 = (p[4] + p[5]) + (p[6] + p[7]);
        float s2 = (p[8] + p[9]) + (p[10] + p[11]);
        float s3 = (p[12] + p[13]) + (p[14] + p[15]);
        l_run += (s0 + s1) + (s2 + s3);

        __builtin_amdgcn_s_setprio(1);
        #pragma unroll
        for (int ki = 0; ki < 4; ++ki) {
            union { bf16x4 v; unsigned u[2]; } pf;
            pf.u[0] = pk2(p[ki * 4 + 0], p[ki * 4 + 1]);
            pf.u[1] = pk2(p[ki * 4 + 2], p[ki * 4 + 3]);
            #pragma unroll
            for (int q = 0; q < 4; ++q) {
                bf16x4 vf = *(const bf16x4*)&Vt[cur][16 * q + lq][ki * 16 + 4 * g];
                o[q] = __builtin_amdgcn_mfma_f32_16x16x16bf16_1k(vf, pf.v, o[q], 0, 0, 0);
            }
        }
        __builtin_amdgcn_s_setprio(0);

        if (has_next) {
            const int nxt = cur ^ 1;
            *(bf16x8*)&Kt[nxt][skey][sdq] = cvt8(kr0, kr1);
            *(bf16x8*)&Kt[nxt][skey][sdq + 8] = cvt8(kr2, kr3);
            float av[8] = {vr0.x, vr0.y, vr0.z, vr0.w, vr1.x, vr1.y, vr1.z, vr1.w};
            float bv[8] = {vr2.x, vr2.y, vr2.z, vr2.w, vr3.x, vr3.y, vr3.z, vr3.w};
            #pragma unroll
            for (int jj = 0; jj < 8; ++jj)
                *(unsigned*)&Vt[nxt][8 * dvg + jj][2 * p_] = pk2(av[jj], bv[jj]);
        }
        __syncthreads();
    }

    l_run += __shfl_xor(l_run, 16, 64);
    l_run += __shfl_xor(l_run, 32, 64);
    float inv = __builtin_amdgcn_rcpf(l_run);
    float* orow = out + ((size_t)b * LL + qbase + lq) * DM + h * DH;
    #pragma unroll
    for (int t = 0; t < 4; ++t) {
        float4 ov;
        ov.x = o[t][0] * inv; ov.y = o[t][1] * inv;
        ov.z = o[t][2] * inv; ov.w = o[t][3] * inv;
        *(float4*)(orow + 16 * t + 4 * g) = ov;
    }
}

extern "C" void kernel_launch(void* const* d_in, const int* in_sizes, int n_in,
                              void* d_out, int out_size, void* d_ws, size_t ws_size,
                              hipStream_t stream) {
    const float* Q = (const float*)d_in[0];
    const float* K = (const float*)d_in[1];
    const float* V = (const float*)d_in[2];
    const void* mask = d_in[3];
    float* out = (float*)d_out;

    unsigned* bits = (unsigned*)d_ws;                           // 1 MB
    const size_t MASK_B = (size_t)2 * LL * 64 * 4;              // 1048576
    const size_t KV_B = (size_t)2 * NH * 32 * 4096 * 2;         // 8 MB each
    short* Kb = (short*)((char*)d_ws + MASK_B);
    short* Vb = (short*)((char*)d_ws + MASK_B + KV_B);

    pack_mask<<<dim3(2 * LL * 64 / 256), dim3(256), 0, stream>>>(mask, bits);

    if (ws_size >= MASK_B + 2 * KV_B) {
        prep_k<<<dim3(32, NH, 2), dim3(256), 0, stream>>>(K, Kb);
        prep_v<<<dim3(32, NH, 2), dim3(256), 0, stream>>>(V, Vb);
        mha_fwd2<<<dim3(512), dim3(512), 0, stream>>>(Q, Kb, Vb, bits, out);
    } else {
        dim3 grid(LL / 64, NH, 2);
        mha_fwd<<<grid, dim3(256), 0, stream>>>(Q, K, V, bits, out);
    }
}

// Round 7
// 104.291 us; speedup vs baseline: 1.3934x; 1.0436x over previous
//
#include <hip/hip_runtime.h>
#include <hip/hip_bf16.h>

#define NH 16
#define DH 64
#define LL 2048
#define DM 1024
#define SCALE2 0.1803368801111204f   /* 0.125 * log2(e) */
#define M_STATIC 10.0f               /* static log2-domain softmax shift */
#define THR_C 6.0f                   /* guard fires only if score > ~11 sigma */
#define NT (LL / 64)
#define NT2 (LL / 128)

typedef __attribute__((ext_vector_type(4))) float f32x4;
typedef __attribute__((ext_vector_type(8))) short bf16x8;
typedef __attribute__((ext_vector_type(4))) short bf16x4;

__device__ __forceinline__ unsigned pk2(float lo, float hi) {
    __hip_bfloat162 h = __float22bfloat162_rn(make_float2(lo, hi));
    union { __hip_bfloat162 h; unsigned u; } c; c.h = h; return c.u;
}
__device__ __forceinline__ bf16x8 cvt8(float4 a, float4 b) {
    union { bf16x8 v; unsigned u[4]; } r;
    r.u[0] = pk2(a.x, a.y); r.u[1] = pk2(a.z, a.w);
    r.u[2] = pk2(b.x, b.y); r.u[3] = pk2(b.z, b.w);
    return r.v;
}

// ---- mask pre-pack: [B][L][L] (int32 or byte bool) -> bit per key ----
__global__ __launch_bounds__(256) void pack_mask(const void* __restrict__ mask,
                                                 unsigned* __restrict__ bits)
{
    const int tid = threadIdx.x;
    const int lane = tid & 63;
    const int* mw = (const int*)mask;
    unsigned long long bad = __ballot((unsigned)mw[lane] > 1u);
    const bool is_int = (bad == 0ULL);

    const int wid = blockIdx.x * 256 + tid;   // 0 .. 2*LL*64-1
    const int q64 = wid >> 6;
    const int w = wid & 63;
    unsigned m = 0;
    if (is_int) {
        const int* p = (const int*)mask + (size_t)q64 * LL + w * 32;
        #pragma unroll
        for (int j = 0; j < 32; j += 4) {
            int4 v = *(const int4*)(p + j);
            m |= (v.x ? 1u : 0u) << j;
            m |= (v.y ? 1u : 0u) << (j + 1);
            m |= (v.z ? 1u : 0u) << (j + 2);
            m |= (v.w ? 1u : 0u) << (j + 3);
        }
    } else {
        const unsigned* p = (const unsigned*)((const unsigned char*)mask
                                              + (size_t)q64 * LL + w * 32);
        #pragma unroll
        for (int j = 0; j < 8; ++j) {
            unsigned v = p[j];
            m |= (v & 1u) << (4 * j);
            m |= ((v >> 8) & 1u) << (4 * j + 1);
            m |= ((v >> 16) & 1u) << (4 * j + 2);
            m |= ((v >> 24) & 1u) << (4 * j + 3);
        }
    }
    bits[wid] = m;
}

// ---- K pre-convert: f32 -> bf16, 8KB per (b,h,ktile), swizzled LDS image ----
// logical (key 0..63, col 0..63) -> tile[key*64 + ((col>>3)^(key&7))*8 + (col&7)]
__global__ __launch_bounds__(256) void prep_k(const float* __restrict__ K,
                                              short* __restrict__ Kb)
{
    const int kt = blockIdx.x, h = blockIdx.y, b = blockIdx.z;
    const int tid = threadIdx.x;
    const int key = tid >> 2;
    const int c8 = (tid & 3) * 2;
    const float* src = K + ((size_t)b * LL + kt * 64 + key) * DM + h * DH + c8 * 8;
    float4 a = *(const float4*)(src);
    float4 bb = *(const float4*)(src + 4);
    float4 c = *(const float4*)(src + 8);
    float4 d = *(const float4*)(src + 12);
    short* dst = Kb + (((size_t)(b * NH + h) * 32 + kt) << 12);
    *(bf16x8*)&dst[key * 64 + ((c8 ^ (key & 7)) << 3)] = cvt8(a, bb);
    *(bf16x8*)&dst[key * 64 + (((c8 + 1) ^ (key & 7)) << 3)] = cvt8(c, d);
}

// ---- V pre-convert: f32 -> bf16 transposed V^T, swizzled LDS image ----
// logical (dv 0..63, key 0..63) -> tile[dv*64 + ((key>>2)^(dv&15))*4 + (key&3)]
__global__ __launch_bounds__(256) void prep_v(const float* __restrict__ V,
                                              short* __restrict__ Vb)
{
    const int kt = blockIdx.x, h = blockIdx.y, b = blockIdx.z;
    const int tid = threadIdx.x;
    const int kp = tid & 31;
    const int dv8 = tid >> 5;
    const float* s0 = V + ((size_t)b * LL + kt * 64 + 2 * kp) * DM + h * DH + dv8 * 8;
    float4 a0 = *(const float4*)(s0);
    float4 a1 = *(const float4*)(s0 + 4);
    float4 b0 = *(const float4*)(s0 + DM);
    float4 b1 = *(const float4*)(s0 + DM + 4);
    float av[8] = {a0.x, a0.y, a0.z, a0.w, a1.x, a1.y, a1.z, a1.w};
    float bv[8] = {b0.x, b0.y, b0.z, b0.w, b1.x, b1.y, b1.z, b1.w};
    short* dst = Vb + (((size_t)(b * NH + h) * 32 + kt) << 12);
    #pragma unroll
    for (int j = 0; j < 8; ++j) {
        int dv = dv8 * 8 + j;
        int off = dv * 64 + (((kp >> 1) ^ (dv & 15)) << 2) + 2 * (kp & 1);
        *(unsigned*)&dst[off] = pk2(av[j], bv[j]);
    }
}

// ---- main: 512 threads, 128 keys/iter (2 sub-tiles), counted vmcnt ----
__global__ __launch_bounds__(512, 4) void mha_fwd2(
    const float* __restrict__ Q, const short* __restrict__ Kb,
    const short* __restrict__ Vb, const unsigned* __restrict__ mbits,
    float* __restrict__ out)
{
    const int bid = blockIdx.x;
    const int xcd = bid & 7;
    const int j = bid >> 3;
    const int pair = xcd * 4 + (j >> 4);
    const int qblk = j & 15;
    const int h = pair & 15;
    const int b = pair >> 4;

    const int tid = threadIdx.x;
    const int w = tid >> 6;
    const int lane = tid & 63;
    const int lq = lane & 15;
    const int g = lane >> 4;

    const int qbase = qblk * 128 + w * 16;

    __shared__ short Kt[2][2][4096];
    __shared__ short Vt[2][2][4096];

    const short* Ktile0 = Kb + ((size_t)(b * NH + h) << 17);
    const short* Vtile0 = Vb + ((size_t)(b * NH + h) << 17);
    const unsigned* Wp = mbits + ((size_t)b * LL + qbase + lq) * 64;

    // prologue: mask(0) first, then the 4 LDS loads of iter 0
    uint4 mreg = *(const uint4*)(Wp);
    #pragma unroll
    for (int sub = 0; sub < 2; ++sub) {
        __builtin_amdgcn_global_load_lds(
            (const unsigned*)(Ktile0 + sub * 4096 + w * 512 + lane * 8),
            (unsigned*)&Kt[0][sub][w * 512], 16, 0, 0);
        __builtin_amdgcn_global_load_lds(
            (const unsigned*)(Vtile0 + sub * 4096 + w * 512 + lane * 8),
            (unsigned*)&Vt[0][sub][w * 512], 16, 0, 0);
    }

    // Q fragments: qf[half][i] = Q[qbase+lq][32*half + 8g + i]
    bf16x8 qf[2];
    {
        const float* qrow = Q + ((size_t)b * LL + qbase + lq) * DM + h * DH;
        #pragma unroll
        for (int half = 0; half < 2; ++half) {
            const float* src = qrow + half * 32 + g * 8;
            qf[half] = cvt8(*(const float4*)(src), *(const float4*)(src + 4));
        }
    }

    f32x4 o[4];
    #pragma unroll
    for (int t = 0; t < 4; ++t) o[t] = (f32x4){0.f, 0.f, 0.f, 0.f};
    float m_run = M_STATIC;
    float l_run = 0.f;

    #pragma unroll 1
    for (int t = 0; t < NT2; ++t) {
        const int cur = t & 1;
        // consume mask(t) BEFORE issuing t+1 loads -> compiler wait = vmcnt(4)
        uint4 m4 = mreg;
        unsigned mw_[4] = {m4.x, m4.y, m4.z, m4.w};
        if (t + 1 < NT2) {
            mreg = *(const uint4*)(Wp + 4 * (t + 1));
            const short* kb = Ktile0 + (size_t)(t + 1) * 8192;
            const short* vb = Vtile0 + (size_t)(t + 1) * 8192;
            #pragma unroll
            for (int sub = 0; sub < 2; ++sub) {
                __builtin_amdgcn_global_load_lds(
                    (const unsigned*)(kb + sub * 4096 + w * 512 + lane * 8),
                    (unsigned*)&Kt[cur ^ 1][sub][w * 512], 16, 0, 0);
                __builtin_amdgcn_global_load_lds(
                    (const unsigned*)(vb + sub * 4096 + w * 512 + lane * 8),
                    (unsigned*)&Vt[cur ^ 1][sub][w * 512], 16, 0, 0);
            }
            // outstanding: 4x gload(t) + mask(t+1) + 4x gload(t+1) = 9
            asm volatile("s_waitcnt vmcnt(5)" ::: "memory");  // drain gload(t) only
        } else {
            asm volatile("s_waitcnt vmcnt(0)" ::: "memory");
        }
        __builtin_amdgcn_s_barrier();
        __builtin_amdgcn_sched_barrier(0);

        // ---- 16 S^T MFMAs (two independent 64-key sub-tiles) ----
        f32x4 s[8];
        __builtin_amdgcn_s_setprio(1);
        #pragma unroll
        for (int sub = 0; sub < 2; ++sub)
            #pragma unroll
            for (int ki = 0; ki < 4; ++ki) {
                const int row = ki * 16 + lq;
                bf16x8 k0 = *(const bf16x8*)
                    &Kt[cur][sub][row * 64 + ((g ^ (lq & 7)) << 3)];
                bf16x8 k1 = *(const bf16x8*)
                    &Kt[cur][sub][row * 64 + (((4 + g) ^ (lq & 7)) << 3)];
                f32x4 acc = (f32x4){0.f, 0.f, 0.f, 0.f};
                acc = __builtin_amdgcn_mfma_f32_16x16x32_bf16(k0, qf[0], acc, 0, 0, 0);
                acc = __builtin_amdgcn_mfma_f32_16x16x32_bf16(k1, qf[1], acc, 0, 0, 0);
                s[sub * 4 + ki] = acc;
            }
        __builtin_amdgcn_s_setprio(0);

        // ---- static-max softmax over 128 keys (log2 domain) ----
        float sv[32];
        #pragma unroll
        for (int i = 0; i < 8; ++i)
            #pragma unroll
            for (int r = 0; r < 4; ++r)
                sv[i * 4 + r] = fmaf(s[i][r], SCALE2, -m_run);

        float h1[16];
        #pragma unroll
        for (int i = 0; i < 16; ++i) h1[i] = fmaxf(sv[2 * i], sv[2 * i + 1]);
        float h2[8];
        #pragma unroll
        for (int i = 0; i < 8; ++i) h2[i] = fmaxf(h1[2 * i], h1[2 * i + 1]);
        float h3[4];
        #pragma unroll
        for (int i = 0; i < 4; ++i) h3[i] = fmaxf(h2[2 * i], h2[2 * i + 1]);
        float pmax = fmaxf(fmaxf(h3[0], h3[1]), fmaxf(h3[2], h3[3]));

        if (!__all(pmax <= THR_C)) {   // rare guard: full shuffled rescale
            float tmax = fmaxf(pmax, __shfl_xor(pmax, 16, 64));
            tmax = fmaxf(tmax, __shfl_xor(tmax, 32, 64));
            float shift = fmaxf(tmax, 0.f);
            float alpha = exp2f(-shift);
            m_run += shift;
            l_run *= alpha;
            #pragma unroll
            for (int q = 0; q < 4; ++q) {
                o[q][0] *= alpha; o[q][1] *= alpha;
                o[q][2] *= alpha; o[q][3] *= alpha;
            }
            #pragma unroll
            for (int i = 0; i < 32; ++i) sv[i] -= shift;
        }

        float p[32];
        #pragma unroll
        for (int i = 0; i < 32; ++i) p[i] = exp2f(sv[i]);
        // mask -> exact zero; word = mw_[sub*2 + (ki>>1)], nib at 16*(ki&1)+4g
        #pragma unroll
        for (int sub = 0; sub < 2; ++sub)
            #pragma unroll
            for (int ki = 0; ki < 4; ++ki) {
                unsigned nib = (mw_[sub * 2 + (ki >> 1)] >> (16 * (ki & 1) + 4 * g)) & 15u;
                #pragma unroll
                for (int r = 0; r < 4; ++r) {
                    int idx = sub * 16 + ki * 4 + r;
                    p[idx] = (nib & (1u << r)) ? 0.f : p[idx];
                }
            }
        float q1[16];
        #pragma unroll
        for (int i = 0; i < 16; ++i) q1[i] = p[2 * i] + p[2 * i + 1];
        float q2[8];
        #pragma unroll
        for (int i = 0; i < 8; ++i) q2[i] = q1[2 * i] + q1[2 * i + 1];
        l_run += ((q2[0] + q2[1]) + (q2[2] + q2[3]))
               + ((q2[4] + q2[5]) + (q2[6] + q2[7]));

        // ---- PV: 32 MFMAs ----
        __builtin_amdgcn_s_setprio(1);
        #pragma unroll
        for (int sub = 0; sub < 2; ++sub)
            #pragma unroll
            for (int ki = 0; ki < 4; ++ki) {
                union { bf16x4 v; unsigned u[2]; } pf;
                pf.u[0] = pk2(p[sub * 16 + ki * 4 + 0], p[sub * 16 + ki * 4 + 1]);
                pf.u[1] = pk2(p[sub * 16 + ki * 4 + 2], p[sub * 16 + ki * 4 + 3]);
                #pragma unroll
                for (int q = 0; q < 4; ++q) {
                    bf16x4 vf = *(const bf16x4*)
                        &Vt[cur][sub][(16 * q + lq) * 64 + (((4 * ki + g) ^ lq) << 2)];
                    o[q] = __builtin_amdgcn_mfma_f32_16x16x16bf16_1k(vf, pf.v, o[q], 0, 0, 0);
                }
            }
        __builtin_amdgcn_s_setprio(0);

        __builtin_amdgcn_sched_barrier(0);
        __builtin_amdgcn_s_barrier();   // reads done before buf reuse
    }

    l_run += __shfl_xor(l_run, 16, 64);
    l_run += __shfl_xor(l_run, 32, 64);
    float inv = __builtin_amdgcn_rcpf(l_run);
    float* orow = out + ((size_t)b * LL + qbase + lq) * DM + h * DH;
    #pragma unroll
    for (int t = 0; t < 4; ++t) {
        float4 ov;
        ov.x = o[t][0] * inv; ov.y = o[t][1] * inv;
        ov.z = o[t][2] * inv; ov.w = o[t][3] * inv;
        *(float4*)(orow + 16 * t + 4 * g) = ov;
    }
}

// ================= fallback (round-6 kernel, ws too small) =================
__global__ __launch_bounds__(256, 4) void mha_fwd(
    const float* __restrict__ Q, const float* __restrict__ K,
    const float* __restrict__ V, const unsigned* __restrict__ mbits,
    float* __restrict__ out)
{
    const int qblk = blockIdx.x;
    const int h = blockIdx.y;
    const int b = blockIdx.z;
    const int tid = threadIdx.x;
    const int w = tid >> 6;
    const int lane = tid & 63;
    const int lq = lane & 15;
    const int g = lane >> 4;

    const int qbase = qblk * 64 + w * 16;
    const float* Qp = Q + ((size_t)b * LL + qbase) * DM + h * DH;
    const float* Kp = K + (size_t)b * LL * DM + h * DH;
    const float* Vp = V + (size_t)b * LL * DM + h * DH;
    const unsigned* Wp = mbits + ((size_t)b * LL + qbase + lq) * 64;

    __shared__ short Kt[2][64][72];
    __shared__ short Vt[2][64][68];

    bf16x8 qf[2];
    {
        const float* qrow = Qp + (size_t)lq * DM;
        #pragma unroll
        for (int half = 0; half < 2; ++half) {
            const float* src = qrow + half * 32 + g * 8;
            qf[half] = cvt8(*(const float4*)(src), *(const float4*)(src + 4));
        }
    }

    f32x4 o[4];
    #pragma unroll
    for (int t = 0; t < 4; ++t) o[t] = (f32x4){0.f, 0.f, 0.f, 0.f};
    float m_run = M_STATIC;
    float l_run = 0.f;

    const int skey = tid >> 2;
    const int sdq = (tid & 3) * 16;
    const int p_ = tid & 31;
    const int dvg = tid >> 5;

    const float* ksrc0 = Kp + (size_t)skey * DM + sdq;
    const float* vsrc0 = Vp + (size_t)(2 * p_) * DM + dvg * 8;

    float4 kr0 = *(const float4*)(ksrc0);
    float4 kr1 = *(const float4*)(ksrc0 + 4);
    float4 kr2 = *(const float4*)(ksrc0 + 8);
    float4 kr3 = *(const float4*)(ksrc0 + 12);
    float4 vr0 = *(const float4*)(vsrc0);
    float4 vr1 = *(const float4*)(vsrc0 + 4);
    float4 vr2 = *(const float4*)(vsrc0 + DM);
    float4 vr3 = *(const float4*)(vsrc0 + DM + 4);
    {
        *(bf16x8*)&Kt[0][skey][sdq] = cvt8(kr0, kr1);
        *(bf16x8*)&Kt[0][skey][sdq + 8] = cvt8(kr2, kr3);
        float av[8] = {vr0.x, vr0.y, vr0.z, vr0.w, vr1.x, vr1.y, vr1.z, vr1.w};
        float bv[8] = {vr2.x, vr2.y, vr2.z, vr2.w, vr3.x, vr3.y, vr3.z, vr3.w};
        #pragma unroll
        for (int jj = 0; jj < 8; ++jj)
            *(unsigned*)&Vt[0][8 * dvg + jj][2 * p_] = pk2(av[jj], bv[jj]);
    }
    __syncthreads();

    #pragma unroll 1
    for (int t = 0; t < NT; ++t) {
        const int cur = t & 1;
        const bool has_next = (t + 1 < NT);
        if (has_next) {
            const float* ks = ksrc0 + (size_t)(t + 1) * 64 * DM;
            const float* vs = vsrc0 + (size_t)(t + 1) * 64 * DM;
            kr0 = *(const float4*)(ks);
            kr1 = *(const float4*)(ks + 4);
            kr2 = *(const float4*)(ks + 8);
            kr3 = *(const float4*)(ks + 12);
            vr0 = *(const float4*)(vs);
            vr1 = *(const float4*)(vs + 4);
            vr2 = *(const float4*)(vs + DM);
            vr3 = *(const float4*)(vs + DM + 4);
        }
        __builtin_amdgcn_sched_barrier(0);

        unsigned long long m64 = *(const unsigned long long*)(Wp + 2 * t);

        f32x4 s[4];
        __builtin_amdgcn_s_setprio(1);
        #pragma unroll
        for (int ki = 0; ki < 4; ++ki) {
            const int row = ki * 16 + lq;
            bf16x8 k0 = *(const bf16x8*)&Kt[cur][row][8 * g];
            bf16x8 k1 = *(const bf16x8*)&Kt[cur][row][32 + 8 * g];
            f32x4 acc = (f32x4){0.f, 0.f, 0.f, 0.f};
            acc = __builtin_amdgcn_mfma_f32_16x16x32_bf16(k0, qf[0], acc, 0, 0, 0);
            acc = __builtin_amdgcn_mfma_f32_16x16x32_bf16(k1, qf[1], acc, 0, 0, 0);
            s[ki] = acc;
        }
        __builtin_amdgcn_s_setprio(0);

        float sv[16];
        #pragma unroll
        for (int ki = 0; ki < 4; ++ki)
            #pragma unroll
            for (int r = 0; r < 4; ++r)
                sv[ki * 4 + r] = fmaf(s[ki][r], SCALE2, -m_run);

        float x0 = fmaxf(fmaxf(sv[0], sv[1]), fmaxf(sv[2], sv[3]));
        float x1 = fmaxf(fmaxf(sv[4], sv[5]), fmaxf(sv[6], sv[7]));
        float x2 = fmaxf(fmaxf(sv[8], sv[9]), fmaxf(sv[10], sv[11]));
        float x3 = fmaxf(fmaxf(sv[12], sv[13]), fmaxf(sv[14], sv[15]));
        float pmax = fmaxf(fmaxf(x0, x1), fmaxf(x2, x3));
        if (!__all(pmax <= THR_C)) {
            float tmax = fmaxf(pmax, __shfl_xor(pmax, 16, 64));
            tmax = fmaxf(tmax, __shfl_xor(tmax, 32, 64));
            float shift = fmaxf(tmax, 0.f);
            float alpha = exp2f(-shift);
            m_run += shift;
            l_run *= alpha;
            #pragma unroll
            for (int q = 0; q < 4; ++q) {
                o[q][0] *= alpha; o[q][1] *= alpha;
                o[q][2] *= alpha; o[q][3] *= alpha;
            }
            #pragma unroll
            for (int i = 0; i < 16; ++i) sv[i] -= shift;
        }

        float p[16];
        #pragma unroll
        for (int i = 0; i < 16; ++i) p[i] = exp2f(sv[i]);
        #pragma unroll
        for (int ki = 0; ki < 4; ++ki) {
            unsigned nib = (unsigned)(m64 >> (ki * 16 + 4 * g)) & 15u;
            #pragma unroll
            for (int r = 0; r < 4; ++r)
                p[ki * 4 + r] = (nib & (1u << r)) ? 0.f : p[ki * 4 + r];
        }
        float s0 = (p[0] + p[1]) + (p[2] + p[3]);
        float s1 = (p[4] + p[5]) + (p[6] + p[7]);
        float s2 = (p[8] + p[9]) + (p[10] + p[11]);
        float s3 = (p[12] + p[13]) + (p[14] + p[15]);
        l_run += (s0 + s1) + (s2 + s3);

        __builtin_amdgcn_s_setprio(1);
        #pragma unroll
        for (int ki = 0; ki < 4; ++ki) {
            union { bf16x4 v; unsigned u[2]; } pf;
            pf.u[0] = pk2(p[ki * 4 + 0], p[ki * 4 + 1]);
            pf.u[1] = pk2(p[ki * 4 + 2], p[ki * 4 + 3]);
            #pragma unroll
            for (int q = 0; q < 4; ++q) {
                bf16x4 vf = *(const bf16x4*)&Vt[cur][16 * q + lq][ki * 16 + 4 * g];
                o[q] = __builtin_amdgcn_mfma_f32_16x16x16bf16_1k(vf, pf.v, o[q], 0, 0, 0);
            }
        }
        __builtin_amdgcn_s_setprio(0);

        if (has_next) {
            const int nxt = cur ^ 1;
            *(bf16x8*)&Kt[nxt][skey][sdq] = cvt8(kr0, kr1);
            *(bf16x8*)&Kt[nxt][skey][sdq + 8] = cvt8(kr2, kr3);
            float av[8] = {vr0.x, vr0.y, vr0.z, vr0.w, vr1.x, vr1.y, vr1.z, vr1.w};
            float bv[8] = {vr2.x, vr2.y, vr2.z, vr2.w, vr3.x, vr3.y, vr3.z, vr3.w};
            #pragma unroll
            for (int jj = 0; jj < 8; ++jj)
                *(unsigned*)&Vt[nxt][8 * dvg + jj][2 * p_] = pk2(av[jj], bv[jj]);
        }
        __syncthreads();
    }

    l_run += __shfl_xor(l_run, 16, 64);
    l_run += __shfl_xor(l_run, 32, 64);
    float inv = __builtin_amdgcn_rcpf(l_run);
    float* orow = out + ((size_t)b * LL + qbase + lq) * DM + h * DH;
    #pragma unroll
    for (int t = 0; t < 4; ++t) {
        float4 ov;
        ov.x = o[t][0] * inv; ov.y = o[t][1] * inv;
        ov.z = o[t][2] * inv; ov.w = o[t][3] * inv;
        *(float4*)(orow + 16 * t + 4 * g) = ov;
    }
}

extern "C" void kernel_launch(void* const* d_in, const int* in_sizes, int n_in,
                              void* d_out, int out_size, void* d_ws, size_t ws_size,
                              hipStream_t stream) {
    const float* Q = (const float*)d_in[0];
    const float* K = (const float*)d_in[1];
    const float* V = (const float*)d_in[2];
    const void* mask = d_in[3];
    float* out = (float*)d_out;

    unsigned* bits = (unsigned*)d_ws;                           // 1 MB
    const size_t MASK_B = (size_t)2 * LL * 64 * 4;              // 1048576
    const size_t KV_B = (size_t)2 * NH * 32 * 4096 * 2;         // 8 MB each
    short* Kb = (short*)((char*)d_ws + MASK_B);
    short* Vb = (short*)((char*)d_ws + MASK_B + KV_B);

    pack_mask<<<dim3(2 * LL * 64 / 256), dim3(256), 0, stream>>>(mask, bits);

    if (ws_size >= MASK_B + 2 * KV_B) {
        prep_k<<<dim3(32, NH, 2), dim3(256), 0, stream>>>(K, Kb);
        prep_v<<<dim3(32, NH, 2), dim3(256), 0, stream>>>(V, Vb);
        mha_fwd2<<<dim3(512), dim3(512), 0, stream>>>(Q, Kb, Vb, bits, out);
    } else {
        dim3 grid(LL / 64, NH, 2);
        mha_fwd<<<grid, dim3(256), 0, stream>>>(Q, K, V, bits, out);
    }
}

// Round 8
// 82.108 us; speedup vs baseline: 1.7699x; 1.2702x over previous
//
#include <hip/hip_runtime.h>
#include <hip/hip_bf16.h>

#define NH 16
#define DH 64
#define LL 2048
#define DM 1024
#define SCALE2 0.1803368801111204f   /* 0.125 * log2(e) */
#define M_STATIC 10.0f               /* static log2-domain softmax shift */
#define THR_C 6.0f                   /* guard fires only if score > ~11 sigma */
#define NT2 (LL / 128)

typedef __attribute__((ext_vector_type(4))) float f32x4;
typedef __attribute__((ext_vector_type(8))) short bf16x8;
typedef __attribute__((ext_vector_type(4))) short bf16x4;

__device__ __forceinline__ unsigned pk2(float lo, float hi) {
    __hip_bfloat162 h = __float22bfloat162_rn(make_float2(lo, hi));
    union { __hip_bfloat162 h; unsigned u; } c; c.h = h; return c.u;
}
__device__ __forceinline__ bf16x8 cvt8(float4 a, float4 b) {
    union { bf16x8 v; unsigned u[4]; } r;
    r.u[0] = pk2(a.x, a.y); r.u[1] = pk2(a.z, a.w);
    r.u[2] = pk2(b.x, b.y); r.u[3] = pk2(b.z, b.w);
    return r.v;
}
__device__ __forceinline__ float exp2_fast(float x) {
    float y;
    asm("v_exp_f32 %0, %1" : "=v"(y) : "v"(x));
    return y;
}

// ---- mask pre-pack, PER-LANE layout ----
// bits[(b*LL+q)*64 + t*4 + g] bit (sub*16+ki*4+r) =
//     mask[b][q][t*128 + sub*64 + ki*16 + 4g + r]
__global__ __launch_bounds__(256) void pack_mask2(const void* __restrict__ mask,
                                                  unsigned* __restrict__ bits)
{
    const int tid = threadIdx.x;
    const int lane = tid & 63;
    const int* mw = (const int*)mask;
    unsigned long long bad = __ballot((unsigned)mw[lane] > 1u);
    const bool is_int = (bad == 0ULL);

    const int wid = blockIdx.x * 256 + tid;   // 0 .. 2*LL*64-1
    const int g = wid & 3;
    const int t = (wid >> 2) & 15;
    const int q64 = wid >> 6;                 // b*LL + q
    unsigned m = 0;
    if (is_int) {
        const int* p = (const int*)mask + (size_t)q64 * LL + t * 128 + 4 * g;
        #pragma unroll
        for (int sub = 0; sub < 2; ++sub)
            #pragma unroll
            for (int ki = 0; ki < 4; ++ki) {
                int4 v = *(const int4*)(p + sub * 64 + ki * 16);
                int base = sub * 16 + ki * 4;
                m |= (v.x ? 1u : 0u) << base;
                m |= (v.y ? 1u : 0u) << (base + 1);
                m |= (v.z ? 1u : 0u) << (base + 2);
                m |= (v.w ? 1u : 0u) << (base + 3);
            }
    } else {
        const unsigned char* pb = (const unsigned char*)mask
                                + (size_t)q64 * LL + t * 128 + 4 * g;
        #pragma unroll
        for (int sub = 0; sub < 2; ++sub)
            #pragma unroll
            for (int ki = 0; ki < 4; ++ki) {
                unsigned v = *(const unsigned*)(pb + sub * 64 + ki * 16);
                int base = sub * 16 + ki * 4;
                m |= (v & 1u) << base;
                m |= ((v >> 8) & 1u) << (base + 1);
                m |= ((v >> 16) & 1u) << (base + 2);
                m |= ((v >> 24) & 1u) << (base + 3);
            }
    }
    bits[wid] = m;
}

// ---- K pre-convert: f32 -> bf16, 8KB per (b,h,ktile), swizzled LDS image ----
// logical (key 0..63, col 0..63) -> tile[key*64 + ((col>>3)^(key&7))*8 + (col&7)]
__global__ __launch_bounds__(256) void prep_k(const float* __restrict__ K,
                                              short* __restrict__ Kb)
{
    const int kt = blockIdx.x, h = blockIdx.y, b = blockIdx.z;
    const int tid = threadIdx.x;
    const int key = tid >> 2;
    const int c8 = (tid & 3) * 2;
    const float* src = K + ((size_t)b * LL + kt * 64 + key) * DM + h * DH + c8 * 8;
    float4 a = *(const float4*)(src);
    float4 bb = *(const float4*)(src + 4);
    float4 c = *(const float4*)(src + 8);
    float4 d = *(const float4*)(src + 12);
    short* dst = Kb + (((size_t)(b * NH + h) * 32 + kt) << 12);
    *(bf16x8*)&dst[key * 64 + ((c8 ^ (key & 7)) << 3)] = cvt8(a, bb);
    *(bf16x8*)&dst[key * 64 + (((c8 + 1) ^ (key & 7)) << 3)] = cvt8(c, d);
}

// ---- V pre-convert: f32 -> bf16 transposed V^T, swizzled LDS image ----
// logical (dv 0..63, key 0..63) -> tile[dv*64 + ((key>>2)^(dv&15))*4 + (key&3)]
__global__ __launch_bounds__(256) void prep_v(const float* __restrict__ V,
                                              short* __restrict__ Vb)
{
    const int kt = blockIdx.x, h = blockIdx.y, b = blockIdx.z;
    const int tid = threadIdx.x;
    const int kp = tid & 31;
    const int dv8 = tid >> 5;
    const float* s0 = V + ((size_t)b * LL + kt * 64 + 2 * kp) * DM + h * DH + dv8 * 8;
    float4 a0 = *(const float4*)(s0);
    float4 a1 = *(const float4*)(s0 + 4);
    float4 b0 = *(const float4*)(s0 + DM);
    float4 b1 = *(const float4*)(s0 + DM + 4);
    float av[8] = {a0.x, a0.y, a0.z, a0.w, a1.x, a1.y, a1.z, a1.w};
    float bv[8] = {b0.x, b0.y, b0.z, b0.w, b1.x, b1.y, b1.z, b1.w};
    short* dst = Vb + (((size_t)(b * NH + h) * 32 + kt) << 12);
    #pragma unroll
    for (int j = 0; j < 8; ++j) {
        int dv = dv8 * 8 + j;
        int off = dv * 64 + (((kp >> 1) ^ (dv & 15)) << 2) + 2 * (kp & 1);
        *(unsigned*)&dst[off] = pk2(av[j], bv[j]);
    }
}

// ---- main: 512 threads, 128 keys/iter, unroll-2, counted vmcnt ----
__global__ __launch_bounds__(512, 4) void mha_fwd2(
    const float* __restrict__ Q, const short* __restrict__ Kb,
    const short* __restrict__ Vb, const unsigned* __restrict__ mbits,
    float* __restrict__ out)
{
    const int bid = blockIdx.x;
    const int xcd = bid & 7;
    const int j = bid >> 3;
    const int pair = xcd * 4 + (j >> 4);
    const int qblk = j & 15;
    const int h = pair & 15;
    const int b = pair >> 4;

    const int tid = threadIdx.x;
    const int w = tid >> 6;
    const int lane = tid & 63;
    const int lq = lane & 15;
    const int g = lane >> 4;

    const int qbase = qblk * 128 + w * 16;

    __shared__ short Kt[2][2][4096];
    __shared__ short Vt[2][2][4096];

    const short* Ktile0 = Kb + ((size_t)(b * NH + h) << 17);
    const short* Vtile0 = Vb + ((size_t)(b * NH + h) << 17);
    // per-lane mask words, stride 16B per iter
    const unsigned* Mp = mbits + ((size_t)b * LL + qbase + lq) * 64 + g;

    // prologue: mask(0) + tile-0 LDS loads
    unsigned mnext = Mp[0];
    #pragma unroll
    for (int sub = 0; sub < 2; ++sub) {
        __builtin_amdgcn_global_load_lds(
            (const unsigned*)(Ktile0 + sub * 4096 + w * 512 + lane * 8),
            (unsigned*)&Kt[0][sub][w * 512], 16, 0, 0);
        __builtin_amdgcn_global_load_lds(
            (const unsigned*)(Vtile0 + sub * 4096 + w * 512 + lane * 8),
            (unsigned*)&Vt[0][sub][w * 512], 16, 0, 0);
    }

    // Q fragments, PRE-SCALED by SCALE2: qf[half][i] = SCALE2*Q[qbase+lq][32h+8g+i]
    bf16x8 qf[2];
    {
        const float* qrow = Q + ((size_t)b * LL + qbase + lq) * DM + h * DH;
        #pragma unroll
        for (int half = 0; half < 2; ++half) {
            const float* src = qrow + half * 32 + g * 8;
            float4 a = *(const float4*)(src);
            float4 c = *(const float4*)(src + 4);
            a.x *= SCALE2; a.y *= SCALE2; a.z *= SCALE2; a.w *= SCALE2;
            c.x *= SCALE2; c.y *= SCALE2; c.z *= SCALE2; c.w *= SCALE2;
            qf[half] = cvt8(a, c);
        }
    }

    f32x4 o[4];
    #pragma unroll
    for (int t = 0; t < 4; ++t) o[t] = (f32x4){0.f, 0.f, 0.f, 0.f};
    f32x4 l_acc = (f32x4){0.f, 0.f, 0.f, 0.f};
    float m_run = M_STATIC;
    const bf16x4 ones = {(short)0x3F80, (short)0x3F80, (short)0x3F80, (short)0x3F80};

    asm volatile("s_waitcnt vmcnt(0)" ::: "memory");
    __builtin_amdgcn_s_barrier();

    #pragma unroll 2
    for (int t = 0; t < NT2; ++t) {
        const int cur = t & 1;
        const unsigned mword = mnext;
        if (t + 1 < NT2) {
            mnext = Mp[(t + 1) * 4];
            const short* kb = Ktile0 + (size_t)(t + 1) * 8192;
            const short* vb = Vtile0 + (size_t)(t + 1) * 8192;
            #pragma unroll
            for (int sub = 0; sub < 2; ++sub) {
                __builtin_amdgcn_global_load_lds(
                    (const unsigned*)(kb + sub * 4096 + w * 512 + lane * 8),
                    (unsigned*)&Kt[cur ^ 1][sub][w * 512], 16, 0, 0);
                __builtin_amdgcn_global_load_lds(
                    (const unsigned*)(vb + sub * 4096 + w * 512 + lane * 8),
                    (unsigned*)&Vt[cur ^ 1][sub][w * 512], 16, 0, 0);
            }
            asm volatile("s_waitcnt vmcnt(5)" ::: "memory");  // drain tile t only
        } else {
            asm volatile("s_waitcnt vmcnt(0)" ::: "memory");
        }
        __builtin_amdgcn_s_barrier();
        __builtin_amdgcn_sched_barrier(0);

        // ---- 16 S^T MFMAs (Q pre-scaled => s already in log2 domain) ----
        f32x4 s[8];
        __builtin_amdgcn_s_setprio(1);
        #pragma unroll
        for (int sub = 0; sub < 2; ++sub)
            #pragma unroll
            for (int ki = 0; ki < 4; ++ki) {
                const int row = ki * 16 + lq;
                bf16x8 k0 = *(const bf16x8*)
                    &Kt[cur][sub][row * 64 + ((g ^ (lq & 7)) << 3)];
                bf16x8 k1 = *(const bf16x8*)
                    &Kt[cur][sub][row * 64 + (((4 + g) ^ (lq & 7)) << 3)];
                f32x4 acc = (f32x4){0.f, 0.f, 0.f, 0.f};
                acc = __builtin_amdgcn_mfma_f32_16x16x32_bf16(k0, qf[0], acc, 0, 0, 0);
                acc = __builtin_amdgcn_mfma_f32_16x16x32_bf16(k1, qf[1], acc, 0, 0, 0);
                s[sub * 4 + ki] = acc;
            }
        __builtin_amdgcn_s_setprio(0);

        // ---- static-max softmax ----
        f32x4 sv[8];
        #pragma unroll
        for (int i = 0; i < 8; ++i) sv[i] = s[i] - m_run;

        f32x4 mx = sv[0];
        #pragma unroll
        for (int i = 1; i < 8; ++i) {
            mx[0] = fmaxf(mx[0], sv[i][0]);
            mx[1] = fmaxf(mx[1], sv[i][1]);
            mx[2] = fmaxf(mx[2], sv[i][2]);
            mx[3] = fmaxf(mx[3], sv[i][3]);
        }
        float pmax = fmaxf(fmaxf(mx[0], mx[1]), fmaxf(mx[2], mx[3]));
        if (!__all(pmax <= THR_C)) {   // rare guard: full shuffled rescale
            float tmax = fmaxf(pmax, __shfl_xor(pmax, 16, 64));
            tmax = fmaxf(tmax, __shfl_xor(tmax, 32, 64));
            float shift = fmaxf(tmax, 0.f);
            float alpha = exp2_fast(-shift);
            m_run += shift;
            #pragma unroll
            for (int q = 0; q < 4; ++q) {
                o[q][0] *= alpha; o[q][1] *= alpha;
                o[q][2] *= alpha; o[q][3] *= alpha;
            }
            l_acc[0] *= alpha; l_acc[1] *= alpha;
            l_acc[2] *= alpha; l_acc[3] *= alpha;
            #pragma unroll
            for (int i = 0; i < 8; ++i) sv[i] = sv[i] - shift;
        }

        float p_[32];
        #pragma unroll
        for (int i = 0; i < 8; ++i)
            #pragma unroll
            for (int r = 0; r < 4; ++r)
                p_[i * 4 + r] = exp2_fast(sv[i][r]);

        // mask -> exact zero via sign-extended-bit AND (2 VALU/score)
        const unsigned nword = ~mword;
        #pragma unroll
        for (int idx = 0; idx < 32; ++idx) {
            int keep = (int)(nword << (31 - idx)) >> 31;   // 0 or -1
            unsigned pu = __builtin_bit_cast(unsigned, p_[idx]) & (unsigned)keep;
            p_[idx] = __builtin_bit_cast(float, pu);
        }

        // ---- PV + l-accumulate (ones-row MFMA replaces the sum tree) ----
        __builtin_amdgcn_s_setprio(1);
        #pragma unroll
        for (int sub = 0; sub < 2; ++sub)
            #pragma unroll
            for (int ki = 0; ki < 4; ++ki) {
                union { bf16x4 v; unsigned u[2]; } pf;
                pf.u[0] = pk2(p_[sub * 16 + ki * 4 + 0], p_[sub * 16 + ki * 4 + 1]);
                pf.u[1] = pk2(p_[sub * 16 + ki * 4 + 2], p_[sub * 16 + ki * 4 + 3]);
                l_acc = __builtin_amdgcn_mfma_f32_16x16x16bf16_1k(ones, pf.v, l_acc, 0, 0, 0);
                #pragma unroll
                for (int q = 0; q < 4; ++q) {
                    bf16x4 vf = *(const bf16x4*)
                        &Vt[cur][sub][(16 * q + lq) * 64 + (((4 * ki + g) ^ lq) << 2)];
                    o[q] = __builtin_amdgcn_mfma_f32_16x16x16bf16_1k(vf, pf.v, o[q], 0, 0, 0);
                }
            }
        __builtin_amdgcn_s_setprio(0);

        __builtin_amdgcn_sched_barrier(0);
        __builtin_amdgcn_s_barrier();   // reads done before buf reuse
    }

    // l_acc rows are all identical = full row-sum for this lane's q-col
    float inv = __builtin_amdgcn_rcpf(l_acc[0]);
    float* orow = out + ((size_t)b * LL + qbase + lq) * DM + h * DH;
    #pragma unroll
    for (int t = 0; t < 4; ++t) {
        float4 ov;
        ov.x = o[t][0] * inv; ov.y = o[t][1] * inv;
        ov.z = o[t][2] * inv; ov.w = o[t][3] * inv;
        *(float4*)(orow + 16 * t + 4 * g) = ov;
    }
}

extern "C" void kernel_launch(void* const* d_in, const int* in_sizes, int n_in,
                              void* d_out, int out_size, void* d_ws, size_t ws_size,
                              hipStream_t stream) {
    const float* Q = (const float*)d_in[0];
    const float* K = (const float*)d_in[1];
    const float* V = (const float*)d_in[2];
    const void* mask = d_in[3];
    float* out = (float*)d_out;

    unsigned* bits = (unsigned*)d_ws;                           // 1 MB
    const size_t MASK_B = (size_t)2 * LL * 64 * 4;              // 1048576
    const size_t KV_B = (size_t)2 * NH * 32 * 4096 * 2;         // 8 MB each
    short* Kb = (short*)((char*)d_ws + MASK_B);
    short* Vb = (short*)((char*)d_ws + MASK_B + KV_B);

    pack_mask2<<<dim3(2 * LL * 64 / 256), dim3(256), 0, stream>>>(mask, bits);
    prep_k<<<dim3(32, NH, 2), dim3(256), 0, stream>>>(K, Kb);
    prep_v<<<dim3(32, NH, 2), dim3(256), 0, stream>>>(V, Vb);
    mha_fwd2<<<dim3(512), dim3(512), 0, stream>>>(Q, Kb, Vb, bits, out);
}

// Round 9
// 80.695 us; speedup vs baseline: 1.8009x; 1.0175x over previous
//
#include <hip/hip_runtime.h>
#include <hip/hip_bf16.h>

#define NH 16
#define DH 64
#define LL 2048
#define DM 1024
#define SCALE2 0.1803368801111204f   /* 0.125 * log2(e) */
#define GUARD_HI 60.0f               /* overflow guard (~40 sigma) */
#define NT2 (LL / 128)

typedef __attribute__((ext_vector_type(4))) float f32x4;
typedef __attribute__((ext_vector_type(8))) short bf16x8;
typedef __attribute__((ext_vector_type(4))) short bf16x4;

__device__ __forceinline__ unsigned pk2(float lo, float hi) {
    __hip_bfloat162 h = __float22bfloat162_rn(make_float2(lo, hi));
    union { __hip_bfloat162 h; unsigned u; } c; c.h = h; return c.u;
}
__device__ __forceinline__ bf16x8 cvt8(float4 a, float4 b) {
    union { bf16x8 v; unsigned u[4]; } r;
    r.u[0] = pk2(a.x, a.y); r.u[1] = pk2(a.z, a.w);
    r.u[2] = pk2(b.x, b.y); r.u[3] = pk2(b.z, b.w);
    return r.v;
}
__device__ __forceinline__ float exp2_fast(float x) {
    float y;
    asm("v_exp_f32 %0, %1" : "=v"(y) : "v"(x));
    return y;
}
// keep-bit apply: nw bit idx == 1 -> keep p, else 0. Compiles to bfe+and.
__device__ __forceinline__ float keepf(float p, unsigned nw, int idx) {
    int k = (int)(nw << (31 - idx)) >> 31;
    unsigned pu = __builtin_bit_cast(unsigned, p) & (unsigned)k;
    return __builtin_bit_cast(float, pu);
}

// ---- mask pre-pack, PER-LANE layout, INVERTED (bit=1 means KEEP) ----
// bits[(b*LL+q)*64 + t*4 + g] bit (sub*16+ki*4+r) = !mask[b][q][t*128+sub*64+ki*16+4g+r]
__global__ __launch_bounds__(256) void pack_mask2(const void* __restrict__ mask,
                                                  unsigned* __restrict__ bits)
{
    const int tid = threadIdx.x;
    const int lane = tid & 63;
    const int* mw = (const int*)mask;
    unsigned long long bad = __ballot((unsigned)mw[lane] > 1u);
    const bool is_int = (bad == 0ULL);

    const int wid = blockIdx.x * 256 + tid;   // 0 .. 2*LL*64-1
    const int g = wid & 3;
    const int t = (wid >> 2) & 15;
    const int q64 = wid >> 6;                 // b*LL + q
    unsigned m = 0;
    if (is_int) {
        const int* p = (const int*)mask + (size_t)q64 * LL + t * 128 + 4 * g;
        #pragma unroll
        for (int sub = 0; sub < 2; ++sub)
            #pragma unroll
            for (int ki = 0; ki < 4; ++ki) {
                int4 v = *(const int4*)(p + sub * 64 + ki * 16);
                int base = sub * 16 + ki * 4;
                m |= (v.x ? 1u : 0u) << base;
                m |= (v.y ? 1u : 0u) << (base + 1);
                m |= (v.z ? 1u : 0u) << (base + 2);
                m |= (v.w ? 1u : 0u) << (base + 3);
            }
    } else {
        const unsigned char* pb = (const unsigned char*)mask
                                + (size_t)q64 * LL + t * 128 + 4 * g;
        #pragma unroll
        for (int sub = 0; sub < 2; ++sub)
            #pragma unroll
            for (int ki = 0; ki < 4; ++ki) {
                unsigned v = *(const unsigned*)(pb + sub * 64 + ki * 16);
                int base = sub * 16 + ki * 4;
                m |= (v & 1u) << base;
                m |= ((v >> 8) & 1u) << (base + 1);
                m |= ((v >> 16) & 1u) << (base + 2);
                m |= ((v >> 24) & 1u) << (base + 3);
            }
    }
    bits[wid] = ~m;   // inverted: 1 = keep
}

// ---- K pre-convert: f32 -> bf16, 8KB per (b,h,ktile), swizzled LDS image ----
// logical (key 0..63, col 0..63) -> tile[key*64 + ((col>>3)^(key&7))*8 + (col&7)]
__global__ __launch_bounds__(256) void prep_k(const float* __restrict__ K,
                                              short* __restrict__ Kb)
{
    const int kt = blockIdx.x, h = blockIdx.y, b = blockIdx.z;
    const int tid = threadIdx.x;
    const int key = tid >> 2;
    const int c8 = (tid & 3) * 2;
    const float* src = K + ((size_t)b * LL + kt * 64 + key) * DM + h * DH + c8 * 8;
    float4 a = *(const float4*)(src);
    float4 bb = *(const float4*)(src + 4);
    float4 c = *(const float4*)(src + 8);
    float4 d = *(const float4*)(src + 12);
    short* dst = Kb + (((size_t)(b * NH + h) * 32 + kt) << 12);
    *(bf16x8*)&dst[key * 64 + ((c8 ^ (key & 7)) << 3)] = cvt8(a, bb);
    *(bf16x8*)&dst[key * 64 + (((c8 + 1) ^ (key & 7)) << 3)] = cvt8(c, d);
}

// ---- V pre-convert v2: f32 -> bf16 V^T, ki-pair-adjacent swizzled image ----
// key = 16K+4G+j (K=key>>4, G=(key>>2)&3, j=key&3), P=K>>1, c=K&1:
// tile[dv*64 + (((P*4+G) ^ (dv&7))<<3) + c*4 + j]
// -> one b128 read at group ((P*4+g)^(dv&7)) yields ki=2P (shorts 0-3) and
//    ki=2P+1 (shorts 4-7) fragments for lane group g.
__global__ __launch_bounds__(256) void prep_v(const float* __restrict__ V,
                                              short* __restrict__ Vb)
{
    const int kt = blockIdx.x, h = blockIdx.y, b = blockIdx.z;
    const int tid = threadIdx.x;
    const int kp = tid & 31;              // keys 2kp, 2kp+1
    const int dv8 = tid >> 5;
    const float* s0 = V + ((size_t)b * LL + kt * 64 + 2 * kp) * DM + h * DH + dv8 * 8;
    float4 a0 = *(const float4*)(s0);
    float4 a1 = *(const float4*)(s0 + 4);
    float4 b0 = *(const float4*)(s0 + DM);
    float4 b1 = *(const float4*)(s0 + DM + 4);
    float av[8] = {a0.x, a0.y, a0.z, a0.w, a1.x, a1.y, a1.z, a1.w};
    float bv[8] = {b0.x, b0.y, b0.z, b0.w, b1.x, b1.y, b1.z, b1.w};
    short* dst = Vb + (((size_t)(b * NH + h) * 32 + kt) << 12);
    const int grp = ((kp >> 4) << 2) | ((kp >> 1) & 3);   // P*4 + G
    const int sub4 = (((kp >> 3) & 1) << 2) | ((kp & 1) << 1);  // c*4 + j
    #pragma unroll
    for (int j = 0; j < 8; ++j) {
        int dv = dv8 * 8 + j;
        int off = dv * 64 + ((grp ^ (dv & 7)) << 3) + sub4;
        *(unsigned*)&dst[off] = pk2(av[j], bv[j]);
    }
}

// ---- main: 512 threads, 128 keys/iter, unroll-2, counted vmcnt ----
__global__ __launch_bounds__(512, 4) void mha_fwd2(
    const float* __restrict__ Q, const short* __restrict__ Kb,
    const short* __restrict__ Vb, const unsigned* __restrict__ mbits,
    float* __restrict__ out)
{
    const int bid = blockIdx.x;
    const int xcd = bid & 7;
    const int j = bid >> 3;
    const int pair = xcd * 4 + (j >> 4);
    const int qblk = j & 15;
    const int h = pair & 15;
    const int b = pair >> 4;

    const int tid = threadIdx.x;
    const int w = tid >> 6;
    const int lane = tid & 63;
    const int lq = lane & 15;
    const int g = lane >> 4;

    const int qbase = qblk * 128 + w * 16;

    __shared__ short Kt[2][2][4096];
    __shared__ short Vt[2][2][4096];

    const short* Ktile0 = Kb + ((size_t)(b * NH + h) << 17);
    const short* Vtile0 = Vb + ((size_t)(b * NH + h) << 17);
    const unsigned* Mp = mbits + ((size_t)b * LL + qbase + lq) * 64 + g;

    // prologue: mask(0) + tile-0 LDS loads
    unsigned mnext = Mp[0];
    #pragma unroll
    for (int sub = 0; sub < 2; ++sub) {
        __builtin_amdgcn_global_load_lds(
            (const unsigned*)(Ktile0 + sub * 4096 + w * 512 + lane * 8),
            (unsigned*)&Kt[0][sub][w * 512], 16, 0, 0);
        __builtin_amdgcn_global_load_lds(
            (const unsigned*)(Vtile0 + sub * 4096 + w * 512 + lane * 8),
            (unsigned*)&Vt[0][sub][w * 512], 16, 0, 0);
    }

    // Q fragments, PRE-SCALED by SCALE2 (scores emerge in log2 domain)
    bf16x8 qf[2];
    {
        const float* qrow = Q + ((size_t)b * LL + qbase + lq) * DM + h * DH;
        #pragma unroll
        for (int half = 0; half < 2; ++half) {
            const float* src = qrow + half * 32 + g * 8;
            float4 a = *(const float4*)(src);
            float4 c = *(const float4*)(src + 4);
            a.x *= SCALE2; a.y *= SCALE2; a.z *= SCALE2; a.w *= SCALE2;
            c.x *= SCALE2; c.y *= SCALE2; c.z *= SCALE2; c.w *= SCALE2;
            qf[half] = cvt8(a, c);
        }
    }

    f32x4 o[4];
    #pragma unroll
    for (int t = 0; t < 4; ++t) o[t] = (f32x4){0.f, 0.f, 0.f, 0.f};
    f32x4 l_acc = (f32x4){0.f, 0.f, 0.f, 0.f};
    float m_shift = 0.f;    // total shift applied (0 unless guard fired)
    const bf16x4 ones = {(short)0x3F80, (short)0x3F80, (short)0x3F80, (short)0x3F80};

    asm volatile("s_waitcnt vmcnt(0)" ::: "memory");
    __builtin_amdgcn_s_barrier();

    #pragma unroll 2
    for (int t = 0; t < NT2; ++t) {
        const int cur = t & 1;
        const unsigned nword = mnext;   // keep-bits for this iter
        if (t + 1 < NT2) {
            mnext = Mp[(t + 1) * 4];
            const short* kb = Ktile0 + (size_t)(t + 1) * 8192;
            const short* vb = Vtile0 + (size_t)(t + 1) * 8192;
            #pragma unroll
            for (int sub = 0; sub < 2; ++sub) {
                __builtin_amdgcn_global_load_lds(
                    (const unsigned*)(kb + sub * 4096 + w * 512 + lane * 8),
                    (unsigned*)&Kt[cur ^ 1][sub][w * 512], 16, 0, 0);
                __builtin_amdgcn_global_load_lds(
                    (const unsigned*)(vb + sub * 4096 + w * 512 + lane * 8),
                    (unsigned*)&Vt[cur ^ 1][sub][w * 512], 16, 0, 0);
            }
            asm volatile("s_waitcnt vmcnt(5)" ::: "memory");  // drain tile t only
        } else {
            asm volatile("s_waitcnt vmcnt(0)" ::: "memory");
        }
        __builtin_amdgcn_s_barrier();
        __builtin_amdgcn_sched_barrier(0);

        // ---- 16 S^T MFMAs, both sub-tiles ----
        f32x4 sAB[2][4];
        __builtin_amdgcn_s_setprio(1);
        #pragma unroll
        for (int sub = 0; sub < 2; ++sub)
            #pragma unroll
            for (int ki = 0; ki < 4; ++ki) {
                const int row = ki * 16 + lq;
                bf16x8 k0 = *(const bf16x8*)
                    &Kt[cur][sub][row * 64 + ((g ^ (lq & 7)) << 3)];
                bf16x8 k1 = *(const bf16x8*)
                    &Kt[cur][sub][row * 64 + (((4 + g) ^ (lq & 7)) << 3)];
                f32x4 acc = (f32x4){0.f, 0.f, 0.f, 0.f};
                acc = __builtin_amdgcn_mfma_f32_16x16x32_bf16(k0, qf[0], acc, 0, 0, 0);
                acc = __builtin_amdgcn_mfma_f32_16x16x32_bf16(k1, qf[1], acc, 0, 0, 0);
                sAB[sub][ki] = acc;
            }
        __builtin_amdgcn_s_setprio(0);

        // ---- overflow guard (max3-shaped tree; branches never taken in practice)
        float mm[8];
        #pragma unroll
        for (int i = 0; i < 8; ++i) {
            f32x4 v = sAB[i >> 2][i & 3];
            mm[i] = fmaxf(fmaxf(v[0], v[1]), fmaxf(v[2], v[3]));
        }
        float mx = fmaxf(fmaxf(fmaxf(mm[0], mm[1]), fmaxf(mm[2], mm[3])),
                         fmaxf(fmaxf(mm[4], mm[5]), fmaxf(mm[6], mm[7])));
        if (__builtin_expect(m_shift != 0.0f, 0)) {   // sticky slow path
            #pragma unroll
            for (int i = 0; i < 8; ++i) sAB[i >> 2][i & 3] = sAB[i >> 2][i & 3] - m_shift;
            mx -= m_shift;
        }
        if (!__all(mx <= GUARD_HI)) {                 // rare: rescale
            float tmax = fmaxf(mx, __shfl_xor(mx, 16, 64));
            tmax = fmaxf(tmax, __shfl_xor(tmax, 32, 64));
            float shift = tmax - 30.0f;
            m_shift += shift;
            float alpha = exp2_fast(-shift);
            #pragma unroll
            for (int q = 0; q < 4; ++q) {
                o[q][0] *= alpha; o[q][1] *= alpha;
                o[q][2] *= alpha; o[q][3] *= alpha;
            }
            l_acc[0] *= alpha; l_acc[1] *= alpha;
            l_acc[2] *= alpha; l_acc[3] *= alpha;
            #pragma unroll
            for (int i = 0; i < 8; ++i) sAB[i >> 2][i & 3] = sAB[i >> 2][i & 3] - shift;
        }

        // ---- per sub: exp/mask/pack (VALU) then PV (MFMA) — sub1's VALU
        //      overlaps sub0's PV in the pipe ----
        #pragma unroll
        for (int sub = 0; sub < 2; ++sub) {
            union { bf16x4 v; unsigned u[2]; } pf[4];
            #pragma unroll
            for (int ki = 0; ki < 4; ++ki) {
                f32x4 sv = sAB[sub][ki];
                const int base = sub * 16 + ki * 4;
                float p0 = keepf(exp2_fast(sv[0]), nword, base + 0);
                float p1 = keepf(exp2_fast(sv[1]), nword, base + 1);
                float p2 = keepf(exp2_fast(sv[2]), nword, base + 2);
                float p3 = keepf(exp2_fast(sv[3]), nword, base + 3);
                pf[ki].u[0] = pk2(p0, p1);
                pf[ki].u[1] = pk2(p2, p3);
                l_acc = __builtin_amdgcn_mfma_f32_16x16x16bf16_1k(ones, pf[ki].v, l_acc, 0, 0, 0);
            }
            __builtin_amdgcn_s_setprio(1);
            #pragma unroll
            for (int P = 0; P < 2; ++P)
                #pragma unroll
                for (int q = 0; q < 4; ++q) {
                    const int row = 16 * q + lq;
                    bf16x8 v8 = *(const bf16x8*)
                        &Vt[cur][sub][row * 64 + ((((P << 2) + g) ^ (lq & 7)) << 3)];
                    bf16x4 vlo = {v8[0], v8[1], v8[2], v8[3]};
                    bf16x4 vhi = {v8[4], v8[5], v8[6], v8[7]};
                    o[q] = __builtin_amdgcn_mfma_f32_16x16x16bf16_1k(vlo, pf[2 * P].v, o[q], 0, 0, 0);
                    o[q] = __builtin_amdgcn_mfma_f32_16x16x16bf16_1k(vhi, pf[2 * P + 1].v, o[q], 0, 0, 0);
                }
            __builtin_amdgcn_s_setprio(0);
        }

        __builtin_amdgcn_sched_barrier(0);
        __builtin_amdgcn_s_barrier();   // reads done before buf reuse
    }

    // l_acc rows identical = full row-sum for this lane's q-col
    float inv = __builtin_amdgcn_rcpf(l_acc[0]);
    float* orow = out + ((size_t)b * LL + qbase + lq) * DM + h * DH;
    #pragma unroll
    for (int t = 0; t < 4; ++t) {
        float4 ov;
        ov.x = o[t][0] * inv; ov.y = o[t][1] * inv;
        ov.z = o[t][2] * inv; ov.w = o[t][3] * inv;
        *(float4*)(orow + 16 * t + 4 * g) = ov;
    }
}

extern "C" void kernel_launch(void* const* d_in, const int* in_sizes, int n_in,
                              void* d_out, int out_size, void* d_ws, size_t ws_size,
                              hipStream_t stream) {
    const float* Q = (const float*)d_in[0];
    const float* K = (const float*)d_in[1];
    const float* V = (const float*)d_in[2];
    const void* mask = d_in[3];
    float* out = (float*)d_out;

    unsigned* bits = (unsigned*)d_ws;                           // 1 MB
    const size_t MASK_B = (size_t)2 * LL * 64 * 4;              // 1048576
    const size_t KV_B = (size_t)2 * NH * 32 * 4096 * 2;         // 8 MB each
    short* Kb = (short*)((char*)d_ws + MASK_B);
    short* Vb = (short*)((char*)d_ws + MASK_B + KV_B);

    pack_mask2<<<dim3(2 * LL * 64 / 256), dim3(256), 0, stream>>>(mask, bits);
    prep_k<<<dim3(32, NH, 2), dim3(256), 0, stream>>>(K, Kb);
    prep_v<<<dim3(32, NH, 2), dim3(256), 0, stream>>>(V, Vb);
    mha_fwd2<<<dim3(512), dim3(512), 0, stream>>>(Q, Kb, Vb, bits, out);
}